// Round 11
// baseline (388.903 us; speedup 1.0000x reference)
//
#include <hip/hip_runtime.h>

typedef unsigned short u16;
typedef unsigned int u32;
typedef __attribute__((ext_vector_type(8))) short short8;
typedef __attribute__((ext_vector_type(4))) float f32x4;

#define NDIM 256
#define KCAT 512
#define EB 8192      // edges per partition block
#define NBK_MAX 256  // max buckets (node>>8)

__device__ __forceinline__ float bf2f(u16 u) {
  union { u32 i; float f; } v; v.i = ((u32)u) << 16; return v.f;
}
__device__ __forceinline__ u16 f2bf(float f) {
  union { float f; u32 i; } v; v.f = f;
  u32 u = v.i;
  u32 r = (u + 0x7fffu + ((u >> 16) & 1u)) >> 16;  // RNE
  return (u16)r;
}

// Horizontal fusion of all independent setup work (one launch):
//   [0,tA):    cvt fp32->bf16 of both feature tables
//   [tA,tB):   W1 transpose+K-concat (both directions)
//   [tB,tC):   W2 transpose+N-concat (both node types)
//   [tC,tD):   fused layer-2 bias vectors
//   [tD,...):  per-block LDS histogram of dst buckets (radix pass 1)
__global__ void setup_all(
    const float* __restrict__ xd, int n4d, const float* __restrict__ xp, int n4p,
    u16* __restrict__ xd16, u16* __restrict__ xp16,
    const float* __restrict__ W1l0, const float* __restrict__ W1r0, u16* __restrict__ WT10,
    const float* __restrict__ W1l1, const float* __restrict__ W1r1, u16* __restrict__ WT11,
    const float* __restrict__ W2l0, const float* __restrict__ W2r0, u16* __restrict__ WT20,
    const float* __restrict__ W2l1, const float* __restrict__ W2r1, u16* __restrict__ WT21,
    const float* __restrict__ b2d, const float* __restrict__ b2p,
    float* __restrict__ fd, float* __restrict__ fp,
    const int* __restrict__ dpd, const int* __restrict__ pdd, int E,
    int nblk, int nbuckets, int* __restrict__ h0, int* __restrict__ h1,
    int tA, int tB, int tC, int tD) {
  __shared__ int h[NBK_MAX];
  const int b = blockIdx.x;
  const int tid = threadIdx.x;
  if (b < tA) {
    int i = b * 256 + tid;
    const float* in; u16* out; int j;
    if (i < n4d) { in = xd; out = xd16; j = i; }
    else { j = i - n4d; if (j >= n4p) return; in = xp; out = xp16; }
    const float4 v = reinterpret_cast<const float4*>(in)[j];
    u32 lo = (u32)f2bf(v.x) | ((u32)f2bf(v.y) << 16);
    u32 hi = (u32)f2bf(v.z) | ((u32)f2bf(v.w) << 16);
    reinterpret_cast<uint2*>(out)[j] = make_uint2(lo, hi);
  } else if (b < tB) {
    int gidx = (b - tA) * 256 + tid;            // 2 x 131072
    const int sel = gidx >> 17;
    const int idx = gidx & 131071;
    const float* Wl = sel ? W1l1 : W1l0;
    const float* Wr = sel ? W1r1 : W1r0;
    u16* WT = sel ? WT11 : WT10;
    int n = idx >> 9, k = idx & 511;
    float v = (k < 256) ? Wl[k * 256 + n] : Wr[(k - 256) * 256 + n];
    WT[idx] = f2bf(v);
  } else if (b < tC) {
    int gidx = (b - tB) * 256 + tid;            // 2 x 65536
    const int sel = gidx >> 16;
    const int idx = gidx & 65535;
    const float* Wl = sel ? W2l1 : W2l0;
    const float* Wr = sel ? W2r1 : W2r0;
    u16* WT = sel ? WT21 : WT20;
    int n = idx >> 8, k = idx & 255;
    float v = (n < 128) ? Wl[k * 128 + n] : Wr[k * 128 + (n - 128)];
    WT[idx] = f2bf(v);
  } else if (b < tD) {
    fd[tid] = (tid < 128) ? 0.f : b2d[tid - 128];
    fp[tid] = (tid < 128) ? 0.f : b2p[tid - 128];
  } else {
    const int hb = b - tD;
    const int sel = (hb >= nblk);
    const int blk = sel ? hb - nblk : hb;
    const int* dst = sel ? pdd : dpd;
    int* hist = sel ? h1 : h0;
    for (int x = tid; x < nbuckets; x += 256) h[x] = 0;
    __syncthreads();
    const int e0 = blk * EB;
    const int e1 = (e0 + EB < E) ? (e0 + EB) : E;
    for (int i = e0 + tid; i < e1; i += 256) atomicAdd(&h[dst[i] >> 8], 1);
    __syncthreads();
    for (int x = tid; x < nbuckets; x += 256) hist[x * nblk + blk] = h[x];
  }
}

// single-kernel exclusive scan of both hist arrays (one block per direction, 1024 thr)
#define SCAN_PER 20
__global__ void scan_one(const int* __restrict__ h0, int* __restrict__ o0,
                         const int* __restrict__ h1, int* __restrict__ o1, int nh) {
  const int sel = blockIdx.x;
  const int* h = sel ? h1 : h0;
  int* off = sel ? o1 : o0;
  const int tid = threadIdx.x;  // 1024
  int v[SCAN_PER];
  int s = 0;
  const int i0 = tid * SCAN_PER;
#pragma unroll
  for (int j = 0; j < SCAN_PER; ++j) {
    int i = i0 + j;
    v[j] = (i < nh) ? h[i] : 0;
    s += v[j];
  }
  __shared__ int tile[1024];
  tile[tid] = s;
  __syncthreads();
  for (int d = 1; d < 1024; d <<= 1) {
    int t = (tid >= d) ? tile[tid - d] : 0;
    __syncthreads();
    tile[tid] += t;
    __syncthreads();
  }
  int run = tile[tid] - s;  // exclusive prefix of this thread's chunk
#pragma unroll
  for (int j = 0; j < SCAN_PER; ++j) {
    int i = i0 + j;
    run += v[j];
    if (i < nh) off[i + 1] = run;
  }
  if (tid == 0) off[0] = 0;
}

// radix-partition pass 2: LDS cursors = scanned (bucket,blk) offsets -> global slot directly.
__global__ void part_pass(const int* __restrict__ s0, const int* __restrict__ d0, u32* __restrict__ t0,
                          const int* __restrict__ s1, const int* __restrict__ d1, u32* __restrict__ t1,
                          const int* __restrict__ ho0, const int* __restrict__ ho1,
                          int E, int nblk, int nbuckets) {
  const int sel = blockIdx.y;
  const int* src = sel ? s1 : s0;
  const int* dst = sel ? d1 : d0;
  const int* hoff = sel ? ho1 : ho0;
  u32* tmp = sel ? t1 : t0;
  const int blk = blockIdx.x;
  __shared__ int cur[NBK_MAX];
  for (int b = threadIdx.x; b < nbuckets; b += 256) cur[b] = hoff[b * nblk + blk];
  __syncthreads();
  const int e0 = blk * EB;
  const int e1 = (e0 + EB < E) ? (e0 + EB) : E;
  for (int i = e0 + threadIdx.x; i < e1; i += 256) {
    const int d = dst[i];
    const int p = atomicAdd(&cur[d >> 8], 1);
    tmp[p] = ((u32)(d & 255) << 16) | (u32)src[i];
  }
}

// phase C: one block per 256-node bucket; derives per-node off[] (LDS histogram + scan),
// then scatters lst within the bucket's window.
__global__ void bucket_fill(const u32* __restrict__ t0, const int* __restrict__ ho0,
                            int n0, int* __restrict__ off0, int* __restrict__ l0,
                            const u32* __restrict__ t1, const int* __restrict__ ho1,
                            int n1, int* __restrict__ off1, int* __restrict__ l1,
                            int E, int nblk, int nbuckets) {
  const int sel = blockIdx.y;
  const u32* tmp = sel ? t1 : t0;
  const int* hoff = sel ? ho1 : ho0;
  const int n = sel ? n1 : n0;
  int* off = sel ? off1 : off0;
  int* lst = sel ? l1 : l0;
  const int b = blockIdx.x;
  const int node0 = b << 8;
  if (node0 >= n) return;
  const int nodes = (n - node0 < 256) ? (n - node0) : 256;
  const int base = hoff[b * nblk];
  const int bend = hoff[(b + 1) * nblk];
  const int t = threadIdx.x, lane = t & 63, w = t >> 6;
  __shared__ int cnt[256];
  __shared__ int wsum[4];
  cnt[t] = 0;
  __syncthreads();
  for (int i = base + t; i < bend; i += 256) atomicAdd(&cnt[tmp[i] >> 16], 1);
  __syncthreads();
  const int v = cnt[t];
  int inc = v;
#pragma unroll
  for (int d = 1; d < 64; d <<= 1) {
    int x = __shfl_up(inc, d, 64);
    if (lane >= d) inc += x;
  }
  if (lane == 63) wsum[w] = inc;
  __syncthreads();
  int wb = 0;
  for (int q = 0; q < w; ++q) wb += wsum[q];
  const int excl = base + (inc - v) + wb;
  __syncthreads();
  cnt[t] = excl;
  if (t < nodes) off[node0 + t] = excl;
  if (node0 + nodes == n && t == 0) off[n] = E;
  __syncthreads();
  for (int i = base + t; i < bend; i += 256) {
    const u32 pk = tmp[i];
    const int p = atomicAdd(&cnt[pk >> 16], 1);
    lst[p] = (int)(pk & 0xffffu);
  }
}

// one wave per destination node, half-wave per edge (2 edges/iter), uint4 (16B) loads,
// unroll 4 pairs -> 8 edges in flight. Both directions in one launch (blockIdx.y).
// [R6 version — best measured: ~104us, 3.9TB/s gather pattern ceiling (capacity-miss bound)]
__global__ void seg_mean(const u16* __restrict__ f0, const int* __restrict__ o0,
                         const int* __restrict__ l0, u16* __restrict__ out0, int n0,
                         const u16* __restrict__ f1, const int* __restrict__ o1,
                         const int* __restrict__ l1, u16* __restrict__ out1, int n1) {
  const int sel = blockIdx.y;
  const u16* feat = sel ? f1 : f0;
  const int* off = sel ? o1 : o0;
  const int* lst = sel ? l1 : l0;
  u16* out = sel ? out1 : out0;
  const int ndst = sel ? n1 : n0;
  const int wid = threadIdx.x >> 6, lane = threadIdx.x & 63;
  const int node = blockIdx.x * 4 + wid;
  if (node >= ndst) return;
  const int s = off[node], e = off[node + 1];
  const int half = lane >> 5, hl = lane & 31;
  float a[8];
#pragma unroll
  for (int j = 0; j < 8; ++j) a[j] = 0.f;
  int i = s;
  for (; i + 8 <= e; i += 8) {
    const int q0 = lst[i + half], q1 = lst[i + 2 + half];
    const int q2 = lst[i + 4 + half], q3 = lst[i + 6 + half];
    const uint4 v0 = *reinterpret_cast<const uint4*>(feat + (size_t)q0 * NDIM + hl * 8);
    const uint4 v1 = *reinterpret_cast<const uint4*>(feat + (size_t)q1 * NDIM + hl * 8);
    const uint4 v2 = *reinterpret_cast<const uint4*>(feat + (size_t)q2 * NDIM + hl * 8);
    const uint4 v3 = *reinterpret_cast<const uint4*>(feat + (size_t)q3 * NDIM + hl * 8);
    const u32 w0[4] = {v0.x, v0.y, v0.z, v0.w};
    const u32 w1[4] = {v1.x, v1.y, v1.z, v1.w};
    const u32 w2[4] = {v2.x, v2.y, v2.z, v2.w};
    const u32 w3[4] = {v3.x, v3.y, v3.z, v3.w};
#pragma unroll
    for (int q = 0; q < 4; ++q) {
      a[2 * q] += bf2f((u16)(w0[q] & 0xffffu)) + bf2f((u16)(w1[q] & 0xffffu)) +
                  bf2f((u16)(w2[q] & 0xffffu)) + bf2f((u16)(w3[q] & 0xffffu));
      a[2 * q + 1] += bf2f((u16)(w0[q] >> 16)) + bf2f((u16)(w1[q] >> 16)) +
                      bf2f((u16)(w2[q] >> 16)) + bf2f((u16)(w3[q] >> 16));
    }
  }
  for (; i < e; i += 2) {
    if (i + half < e) {
      const int q = lst[i + half];
      const uint4 v = *reinterpret_cast<const uint4*>(feat + (size_t)q * NDIM + hl * 8);
      const u32 w[4] = {v.x, v.y, v.z, v.w};
#pragma unroll
      for (int t = 0; t < 4; ++t) {
        a[2 * t] += bf2f((u16)(w[t] & 0xffffu));
        a[2 * t + 1] += bf2f((u16)(w[t] >> 16));
      }
    }
  }
#pragma unroll
  for (int j = 0; j < 8; ++j) a[j] += __shfl_xor(a[j], 32, 64);
  if (half == 0) {
    const float inv = (e > s) ? 1.f / (float)(e - s) : 0.f;
    uint4 o;
    o.x = (u32)f2bf(a[0] * inv) | ((u32)f2bf(a[1] * inv) << 16);
    o.y = (u32)f2bf(a[2] * inv) | ((u32)f2bf(a[3] * inv) << 16);
    o.z = (u32)f2bf(a[4] * inv) | ((u32)f2bf(a[5] * inv) << 16);
    o.w = (u32)f2bf(a[6] * inv) | ((u32)f2bf(a[7] * inv) << 16);
    *reinterpret_cast<uint4*>(out + (size_t)node * NDIM + hl * 8) = o;
  }
}

// fused layer-2 epilogue: z = l2norm( mean_{src}(ymsg[src]) + yself[node] )
// COMPACT arrays: ymsg[n][128], yself[n][128]. quarter-wave per edge, 8 edges in flight.
__global__ void seg_out(const u16* __restrict__ ym0, const u16* __restrict__ ys0,
                        const int* __restrict__ o0, const int* __restrict__ l0,
                        float* __restrict__ z0, int n0,
                        const u16* __restrict__ ym1, const u16* __restrict__ ys1,
                        const int* __restrict__ o1, const int* __restrict__ l1,
                        float* __restrict__ z1, int n1) {
  const int sel = blockIdx.y;
  const u16* ymsg = sel ? ym1 : ym0;
  const u16* yself = sel ? ys1 : ys0;
  const int* off = sel ? o1 : o0;
  const int* lst = sel ? l1 : l0;
  float* zout = sel ? z1 : z0;
  const int ndst = sel ? n1 : n0;
  const int wid = threadIdx.x >> 6, lane = threadIdx.x & 63;
  const int node = blockIdx.x * 4 + wid;
  if (node >= ndst) return;
  const int s = off[node], e = off[node + 1];
  const int q = lane >> 4, ql = lane & 15;
  float a[8];
#pragma unroll
  for (int j = 0; j < 8; ++j) a[j] = 0.f;
  int i = s;
  for (; i + 8 <= e; i += 8) {
    const int r0 = lst[i + q], r1 = lst[i + 4 + q];
    const uint4 v0 = *reinterpret_cast<const uint4*>(ymsg + (size_t)r0 * 128 + ql * 8);
    const uint4 v1 = *reinterpret_cast<const uint4*>(ymsg + (size_t)r1 * 128 + ql * 8);
    const u32 w0[4] = {v0.x, v0.y, v0.z, v0.w};
    const u32 w1[4] = {v1.x, v1.y, v1.z, v1.w};
#pragma unroll
    for (int c = 0; c < 4; ++c) {
      a[2 * c] += bf2f((u16)(w0[c] & 0xffffu)) + bf2f((u16)(w1[c] & 0xffffu));
      a[2 * c + 1] += bf2f((u16)(w0[c] >> 16)) + bf2f((u16)(w1[c] >> 16));
    }
  }
  for (; i + 4 <= e; i += 4) {
    const int r = lst[i + q];
    const uint4 v = *reinterpret_cast<const uint4*>(ymsg + (size_t)r * 128 + ql * 8);
    const u32 w[4] = {v.x, v.y, v.z, v.w};
#pragma unroll
    for (int c = 0; c < 4; ++c) {
      a[2 * c] += bf2f((u16)(w[c] & 0xffffu));
      a[2 * c + 1] += bf2f((u16)(w[c] >> 16));
    }
  }
  if (i + q < e) {
    const int r = lst[i + q];
    const uint4 v = *reinterpret_cast<const uint4*>(ymsg + (size_t)r * 128 + ql * 8);
    const u32 w[4] = {v.x, v.y, v.z, v.w};
#pragma unroll
    for (int c = 0; c < 4; ++c) {
      a[2 * c] += bf2f((u16)(w[c] & 0xffffu));
      a[2 * c + 1] += bf2f((u16)(w[c] >> 16));
    }
  }
#pragma unroll
  for (int j = 0; j < 8; ++j) {
    a[j] += __shfl_xor(a[j], 16, 64);
    a[j] += __shfl_xor(a[j], 32, 64);
  }
  const float inv = (e > s) ? 1.f / (float)(e - s) : 0.f;
  const uint4 r = *reinterpret_cast<const uint4*>(yself + (size_t)node * 128 + ql * 8);
  const u32 rw[4] = {r.x, r.y, r.z, r.w};
  float z[8];
  float ss = 0.f;
#pragma unroll
  for (int c = 0; c < 4; ++c) {
    z[2 * c] = a[2 * c] * inv + bf2f((u16)(rw[c] & 0xffffu));
    z[2 * c + 1] = a[2 * c + 1] * inv + bf2f((u16)(rw[c] >> 16));
    ss += z[2 * c] * z[2 * c] + z[2 * c + 1] * z[2 * c + 1];
  }
#pragma unroll
  for (int d = 1; d < 16; d <<= 1) ss += __shfl_xor(ss, d, 64);
  const float sc = 1.f / fmaxf(sqrtf(ss), 1e-12f);
  if (q == 0) {
    float4 o0v, o1v;
    o0v.x = z[0] * sc; o0v.y = z[1] * sc; o0v.z = z[2] * sc; o0v.w = z[3] * sc;
    o1v.x = z[4] * sc; o1v.y = z[5] * sc; o1v.z = z[6] * sc; o1v.w = z[7] * sc;
    float* zp = zout + (size_t)node * 128 + ql * 8;
    *reinterpret_cast<float4*>(zp) = o0v;
    *reinterpret_cast<float4*>(zp + 4) = o1v;
  }
}

// 2-phase double-buffered GEMM with COALESCED+SWIZZLED staging, two instances via blockIdx.z.
// C = A @ WT^T + bias. CAT: A = [Am | Ax] K-concat. SPLIT: bf16 out to msg[128]/self[128].
// Staging: 8 lanes cover one row's contiguous 128B (full-line requests); LDS linear
// [row][128B] with pre-swizzled global chunk (chunk^=row&7) + matching XOR on ds_read.
// Pipeline: stage(kt+1 -> buf^1) issued BEFORE compute(kt); ONE barrier per K-step.
// XCD pair swizzle: both N-tiles of an M-tile land on the same XCD (A-panel L2 reuse).
template <bool RELU, bool CAT, int KT, bool SPLIT>
__global__ __launch_bounds__(256) void gemm2(
    const u16* __restrict__ Am0, const u16* __restrict__ Ax0,
    const u16* __restrict__ WT0, const float* __restrict__ bias0,
    u16* __restrict__ out0, u16* __restrict__ outs0, int M0,
    const u16* __restrict__ Am1, const u16* __restrict__ Ax1,
    const u16* __restrict__ WT1, const float* __restrict__ bias1,
    u16* __restrict__ out1, u16* __restrict__ outs1, int M1,
    int gx, int ldb, int ldo) {
  const int raw = blockIdx.x;
  const int xcd = raw & 7, seq = raw >> 3;
  const int ny = seq & 1;
  const int mt = (seq >> 1) * 8 + xcd;
  if (mt >= gx) return;
  const int sel = blockIdx.z;
  const u16* Am = sel ? Am1 : Am0;
  const u16* Ax = sel ? Ax1 : Ax0;
  const u16* WT = sel ? WT1 : WT0;
  const float* bias = sel ? bias1 : bias0;
  u16* out = sel ? out1 : out0;
  u16* outs = sel ? outs1 : outs0;
  const int M = sel ? M1 : M0;
  const int gm0 = mt * 128;
  if (gm0 >= M) return;
  const int n0 = ny * 128;

  __shared__ u16 As[2][8192];  // [buf][row 0..127][64 k-elems = 128B], chunk-swizzled
  __shared__ u16 Bs[2][8192];
  const int tid = threadIdx.x;
  const int wid = tid >> 6, lane = tid & 63;
  const int wr = wid >> 1, wc = wid & 1;

  f32x4 acc[4][4];
  const f32x4 zz = {0.f, 0.f, 0.f, 0.f};
#pragma unroll
  for (int i = 0; i < 4; ++i)
#pragma unroll
    for (int j = 0; j < 4; ++j) acc[i][j] = zz;

  auto stage = [&](int kt, int buf) {
    const u16* Asrc = CAT ? ((kt < KT / 2) ? Am : Ax) : Am;
    const int koff = CAT ? ((kt & (KT / 2 - 1)) * 64) : kt * 64;
#pragma unroll
    for (int t = 0; t < 4; ++t) {
      const int f = wid * 256 + t * 64 + lane;       // 8 lanes per row, coalesced
      const int row = f >> 3;
      const int ch = (f & 7) ^ (row & 7);            // pre-swizzled global chunk
      int grow = gm0 + row; grow = (grow < M) ? grow : (M - 1);
      const u16* g = Asrc + (size_t)grow * NDIM + koff + ch * 8;
      u16* l = &As[buf][(size_t)f * 8];
      __builtin_amdgcn_global_load_lds((const __attribute__((address_space(1))) void*)g,
                                       (__attribute__((address_space(3))) void*)l, 16, 0, 0);
    }
#pragma unroll
    for (int t = 0; t < 4; ++t) {
      const int f = wid * 256 + t * 64 + lane;
      const int n = f >> 3;
      const int ch = (f & 7) ^ (n & 7);
      const u16* g = WT + (size_t)(n0 + n) * ldb + kt * 64 + ch * 8;
      u16* l = &Bs[buf][(size_t)f * 8];
      __builtin_amdgcn_global_load_lds((const __attribute__((address_space(1))) void*)g,
                                       (__attribute__((address_space(3))) void*)l, 16, 0, 0);
    }
  };

  stage(0, 0);
  __syncthreads();  // buf0 ready

  for (int kt = 0; kt < KT; ++kt) {
    const int cur = kt & 1;
    if (kt + 1 < KT) stage(kt + 1, cur ^ 1);  // issue next-tile loads BEFORE compute
#pragma unroll
    for (int ks = 0; ks < 2; ++ks) {
      const int kc = ks * 4 + (lane >> 4);
      short8 a[4], b[4];
#pragma unroll
      for (int mtt = 0; mtt < 4; ++mtt) {
        const int R = wr * 64 + mtt * 16 + (lane & 15);
        a[mtt] = *reinterpret_cast<const short8*>(&As[cur][(size_t)R * 64 + (kc ^ (R & 7)) * 8]);
      }
#pragma unroll
      for (int nt = 0; nt < 4; ++nt) {
        const int N = wc * 64 + nt * 16 + (lane & 15);
        b[nt] = *reinterpret_cast<const short8*>(&Bs[cur][(size_t)N * 64 + (kc ^ (N & 7)) * 8]);
      }
#pragma unroll
      for (int mtt = 0; mtt < 4; ++mtt)
#pragma unroll
        for (int nt = 0; nt < 4; ++nt)
          acc[mtt][nt] = __builtin_amdgcn_mfma_f32_16x16x32_bf16(a[mtt], b[nt], acc[mtt][nt], 0, 0, 0);
    }
    __syncthreads();  // drains next-tile loads; fences reads of cur before overwrite
  }

  const int rw = gm0 + wr * 64;
#pragma unroll
  for (int mtt = 0; mtt < 4; ++mtt) {
#pragma unroll
    for (int j = 0; j < 4; ++j) {
      int row = rw + mtt * 16 + ((lane >> 4) << 2) + j;
      if (row >= M) continue;
#pragma unroll
      for (int nt = 0; nt < 4; ++nt) {
        int col = n0 + wc * 64 + nt * 16 + (lane & 15);
        float v = acc[mtt][nt][j] + bias[col];
        if (RELU) v = fmaxf(v, 0.f);
        if constexpr (SPLIT) {
          if (col < 128) out[(size_t)row * 128 + col] = f2bf(v);
          else outs[(size_t)row * 128 + col - 128] = f2bf(v);
        } else {
          out[(size_t)row * ldo + col] = f2bf(v);
        }
      }
    }
  }
}

extern "C" void kernel_launch(void* const* d_in, const int* in_sizes, int n_in,
                              void* d_out, int out_size, void* d_ws, size_t ws_size,
                              hipStream_t stream) {
  const float* x_drug = (const float*)d_in[0];
  const float* x_prot = (const float*)d_in[1];
  const int* e_dp = (const int*)d_in[2];
  const int* e_pd = (const int*)d_in[3];
  const float* W1l_dp = (const float*)d_in[4];
  const float* W1r_dp = (const float*)d_in[5];
  const float* b1_dp = (const float*)d_in[6];
  const float* W1l_pd = (const float*)d_in[7];
  const float* W1r_pd = (const float*)d_in[8];
  const float* b1_pd = (const float*)d_in[9];
  const float* W2l_dp = (const float*)d_in[10];
  const float* W2r_dp = (const float*)d_in[11];
  const float* b2_dp = (const float*)d_in[12];
  const float* W2l_pd = (const float*)d_in[13];
  const float* W2r_pd = (const float*)d_in[14];
  const float* b2_pd = (const float*)d_in[15];

  const int E = in_sizes[2] / 2;
  const int ND = in_sizes[0] / NDIM;
  const int NP = in_sizes[1] / NDIM;

  const int* dp_src = e_dp;       // drug indices
  const int* dp_dst = e_dp + E;   // protein indices
  const int* pd_src = e_pd;       // protein indices
  const int* pd_dst = e_pd + E;   // drug indices

  char* ws = (char*)d_ws;
  size_t o = 0;
  auto alloc = [&](size_t bytes) -> void* {
    void* p = ws + o;
    o = (o + bytes + 255) & ~(size_t)255;
    return p;
  };
  u16* xd16 = (u16*)alloc((size_t)ND * NDIM * 2);
  u16* xp16 = (u16*)alloc((size_t)NP * NDIM * 2);
  u16* mp16 = (u16*)alloc((size_t)NP * NDIM * 2);  // means; reused as ymsg_p/yself_p
  u16* md16 = (u16*)alloc((size_t)ND * NDIM * 2);  // means; reused as ymsg_d/yself_d
  u16* hp16 = (u16*)alloc((size_t)NP * NDIM * 2);
  u16* hd16 = (u16*)alloc((size_t)ND * NDIM * 2);
  u16* wt1dp = (u16*)alloc((size_t)256 * KCAT * 2);
  u16* wt1pd = (u16*)alloc((size_t)256 * KCAT * 2);
  u16* wt2d = (u16*)alloc((size_t)256 * 256 * 2);  // [W2l_dp | W2r_pd] for drugs
  u16* wt2p = (u16*)alloc((size_t)256 * 256 * 2);  // [W2l_pd | W2r_dp] for proteins
  float* fbias_d = (float*)alloc(256 * 4);
  float* fbias_p = (float*)alloc(256 * 4);
  int* off_dp = (int*)alloc((size_t)(NP + 1) * 4);
  int* off_pd = (int*)alloc((size_t)(ND + 1) * 4);
  int* lst_dp = (int*)alloc((size_t)E * 4);
  int* lst_pd = (int*)alloc((size_t)E * 4);
  u32* tmp_dp = (u32*)alloc((size_t)E * 4);
  u32* tmp_pd = (u32*)alloc((size_t)E * 4);

  const int nmax = (NP > ND) ? NP : ND;
  const int nbuckets = (nmax + 255) >> 8;
  const int nblk = (E + EB - 1) / EB;
  const int nh = nbuckets * nblk;
  int* hist0 = (int*)alloc((size_t)nh * 4);
  int* hist1 = (int*)alloc((size_t)nh * 4);
  int* hoff0 = (int*)alloc((size_t)(nh + 1) * 4);
  int* hoff1 = (int*)alloc((size_t)(nh + 1) * 4);

  dim3 blk(256);

  // fused setup: cvt + W1/W2 prep + fbias + radix histogram, one launch
  const int n4d = ND * NDIM / 4, n4p = NP * NDIM / 4;
  const int tA = (n4d + n4p + 255) / 256;
  const int tB = tA + (2 * 256 * KCAT + 255) / 256;
  const int tC = tB + (2 * 256 * 256 + 255) / 256;
  const int tD = tC + 1;
  const int tTotal = tD + 2 * nblk;
  setup_all<<<tTotal, blk, 0, stream>>>(
      x_drug, n4d, x_prot, n4p, xd16, xp16,
      W1l_dp, W1r_dp, wt1dp, W1l_pd, W1r_pd, wt1pd,
      W2l_dp, W2r_pd, wt2d, W2l_pd, W2r_dp, wt2p,
      b2_pd, b2_dp, fbias_d, fbias_p,
      dp_dst, pd_dst, E, nblk, nbuckets, hist0, hist1,
      tA, tB, tC, tD);

  // single-kernel scan of both hist arrays
  scan_one<<<2, 1024, 0, stream>>>(hist0, hoff0, hist1, hoff1, nh);

  part_pass<<<dim3(nblk, 2), blk, 0, stream>>>(
      dp_src, dp_dst, tmp_dp, pd_src, pd_dst, tmp_pd, hoff0, hoff1, E, nblk, nbuckets);
  bucket_fill<<<dim3(nbuckets, 2), blk, 0, stream>>>(
      tmp_dp, hoff0, NP, off_dp, lst_dp, tmp_pd, hoff1, ND, off_pd, lst_pd, E, nblk, nbuckets);

  // layer 1: mean aggregation of raw features (both directions, one launch)
  seg_mean<<<dim3((nmax + 3) / 4, 2), blk, 0, stream>>>(
      xd16, off_dp, lst_dp, mp16, NP, xp16, off_pd, lst_pd, md16, ND);

  // GEMM grid: swizzled pairs, 8-aligned
  const int gx = (nmax + 127) / 128;
  const int gridx = ((gx + 7) / 8) * 16;  // mgrps*2*8

  // layer 1 GEMMs: h = relu([mean | x] @ W1cat + b)   (both node types via z)
  gemm2<true, true, 8, false><<<dim3(gridx, 1, 2), blk, 0, stream>>>(
      mp16, xp16, wt1dp, b1_dp, hp16, (u16*)nullptr, NP,
      md16, xd16, wt1pd, b1_pd, hd16, (u16*)nullptr, ND, gx, KCAT, 256);

  // layer 2 transform-first, COMPACT split outputs: ymsg[n][128], yself[n][128]
  u16* ymsg_d = md16;
  u16* yself_d = md16 + (size_t)ND * 128;
  u16* ymsg_p = mp16;
  u16* yself_p = mp16 + (size_t)NP * 128;
  gemm2<false, false, 4, true><<<dim3(gridx, 1, 2), blk, 0, stream>>>(
      hd16, hd16, wt2d, fbias_d, ymsg_d, yself_d, ND,
      hp16, hp16, wt2p, fbias_p, ymsg_p, yself_p, NP, gx, 256, 256);

  // fused: mean-gather of compact messages + self + L2 normalize -> d_out
  float* zd = (float*)d_out;
  float* zp = zd + (size_t)ND * 128;
  seg_out<<<dim3((nmax + 3) / 4, 2), blk, 0, stream>>>(
      ymsg_p, yself_d, off_pd, lst_pd, zd, ND, ymsg_d, yself_p, off_dp, lst_dp, zp, NP);
}

// Round 12
// 378.634 us; speedup vs baseline: 1.0271x; 1.0271x over previous
//
#include <hip/hip_runtime.h>

typedef unsigned short u16;
typedef unsigned int u32;
typedef __attribute__((ext_vector_type(8))) short short8;
typedef __attribute__((ext_vector_type(4))) float f32x4;

#define NDIM 256
#define KCAT 512
#define EB 8192      // edges per partition block
#define NBK_MAX 256  // max buckets (node>>8)

__device__ __forceinline__ float bf2f(u16 u) {
  union { u32 i; float f; } v; v.i = ((u32)u) << 16; return v.f;
}
__device__ __forceinline__ u16 f2bf(float f) {
  union { float f; u32 i; } v; v.f = f;
  u32 u = v.i;
  u32 r = (u + 0x7fffu + ((u >> 16) & 1u)) >> 16;  // RNE
  return (u16)r;
}

// Horizontal fusion of all independent setup work (one launch):
//   [0,tA):    cvt fp32->bf16 of both feature tables
//   [tA,tB):   W1 transpose+K-concat (both directions)
//   [tB,tC):   W2 transpose+N-concat (both node types)
//   [tC,tD):   fused layer-2 bias vectors
//   [tD,...):  per-block LDS histogram of dst buckets (radix pass 1)
__global__ void setup_all(
    const float* __restrict__ xd, int n4d, const float* __restrict__ xp, int n4p,
    u16* __restrict__ xd16, u16* __restrict__ xp16,
    const float* __restrict__ W1l0, const float* __restrict__ W1r0, u16* __restrict__ WT10,
    const float* __restrict__ W1l1, const float* __restrict__ W1r1, u16* __restrict__ WT11,
    const float* __restrict__ W2l0, const float* __restrict__ W2r0, u16* __restrict__ WT20,
    const float* __restrict__ W2l1, const float* __restrict__ W2r1, u16* __restrict__ WT21,
    const float* __restrict__ b2d, const float* __restrict__ b2p,
    float* __restrict__ fd, float* __restrict__ fp,
    const int* __restrict__ dpd, const int* __restrict__ pdd, int E,
    int nblk, int nbuckets, int* __restrict__ h0, int* __restrict__ h1,
    int tA, int tB, int tC, int tD) {
  __shared__ int h[NBK_MAX];
  const int b = blockIdx.x;
  const int tid = threadIdx.x;
  if (b < tA) {
    int i = b * 256 + tid;
    const float* in; u16* out; int j;
    if (i < n4d) { in = xd; out = xd16; j = i; }
    else { j = i - n4d; if (j >= n4p) return; in = xp; out = xp16; }
    const float4 v = reinterpret_cast<const float4*>(in)[j];
    u32 lo = (u32)f2bf(v.x) | ((u32)f2bf(v.y) << 16);
    u32 hi = (u32)f2bf(v.z) | ((u32)f2bf(v.w) << 16);
    reinterpret_cast<uint2*>(out)[j] = make_uint2(lo, hi);
  } else if (b < tB) {
    int gidx = (b - tA) * 256 + tid;            // 2 x 131072
    const int sel = gidx >> 17;
    const int idx = gidx & 131071;
    const float* Wl = sel ? W1l1 : W1l0;
    const float* Wr = sel ? W1r1 : W1r0;
    u16* WT = sel ? WT11 : WT10;
    int n = idx >> 9, k = idx & 511;
    float v = (k < 256) ? Wl[k * 256 + n] : Wr[(k - 256) * 256 + n];
    WT[idx] = f2bf(v);
  } else if (b < tC) {
    int gidx = (b - tB) * 256 + tid;            // 2 x 65536
    const int sel = gidx >> 16;
    const int idx = gidx & 65535;
    const float* Wl = sel ? W2l1 : W2l0;
    const float* Wr = sel ? W2r1 : W2r0;
    u16* WT = sel ? WT21 : WT20;
    int n = idx >> 8, k = idx & 255;
    float v = (n < 128) ? Wl[k * 128 + n] : Wr[k * 128 + (n - 128)];
    WT[idx] = f2bf(v);
  } else if (b < tD) {
    fd[tid] = (tid < 128) ? 0.f : b2d[tid - 128];
    fp[tid] = (tid < 128) ? 0.f : b2p[tid - 128];
  } else {
    const int hb = b - tD;
    const int sel = (hb >= nblk);
    const int blk = sel ? hb - nblk : hb;
    const int* dst = sel ? pdd : dpd;
    int* hist = sel ? h1 : h0;
    for (int x = tid; x < nbuckets; x += 256) h[x] = 0;
    __syncthreads();
    const int e0 = blk * EB;
    const int e1 = (e0 + EB < E) ? (e0 + EB) : E;
    for (int i = e0 + tid; i < e1; i += 256) atomicAdd(&h[dst[i] >> 8], 1);
    __syncthreads();
    for (int x = tid; x < nbuckets; x += 256) hist[x * nblk + blk] = h[x];
  }
}

// single-kernel exclusive scan of both hist arrays (one block per direction, 1024 thr)
#define SCAN_PER 20
__global__ void scan_one(const int* __restrict__ h0, int* __restrict__ o0,
                         const int* __restrict__ h1, int* __restrict__ o1, int nh) {
  const int sel = blockIdx.x;
  const int* h = sel ? h1 : h0;
  int* off = sel ? o1 : o0;
  const int tid = threadIdx.x;  // 1024
  int v[SCAN_PER];
  int s = 0;
  const int i0 = tid * SCAN_PER;
#pragma unroll
  for (int j = 0; j < SCAN_PER; ++j) {
    int i = i0 + j;
    v[j] = (i < nh) ? h[i] : 0;
    s += v[j];
  }
  __shared__ int tile[1024];
  tile[tid] = s;
  __syncthreads();
  for (int d = 1; d < 1024; d <<= 1) {
    int t = (tid >= d) ? tile[tid - d] : 0;
    __syncthreads();
    tile[tid] += t;
    __syncthreads();
  }
  int run = tile[tid] - s;  // exclusive prefix of this thread's chunk
#pragma unroll
  for (int j = 0; j < SCAN_PER; ++j) {
    int i = i0 + j;
    run += v[j];
    if (i < nh) off[i + 1] = run;
  }
  if (tid == 0) off[0] = 0;
}

// radix-partition pass 2: LDS cursors = scanned (bucket,blk) offsets -> global slot directly.
__global__ void part_pass(const int* __restrict__ s0, const int* __restrict__ d0, u32* __restrict__ t0,
                          const int* __restrict__ s1, const int* __restrict__ d1, u32* __restrict__ t1,
                          const int* __restrict__ ho0, const int* __restrict__ ho1,
                          int E, int nblk, int nbuckets) {
  const int sel = blockIdx.y;
  const int* src = sel ? s1 : s0;
  const int* dst = sel ? d1 : d0;
  const int* hoff = sel ? ho1 : ho0;
  u32* tmp = sel ? t1 : t0;
  const int blk = blockIdx.x;
  __shared__ int cur[NBK_MAX];
  for (int b = threadIdx.x; b < nbuckets; b += 256) cur[b] = hoff[b * nblk + blk];
  __syncthreads();
  const int e0 = blk * EB;
  const int e1 = (e0 + EB < E) ? (e0 + EB) : E;
  for (int i = e0 + threadIdx.x; i < e1; i += 256) {
    const int d = dst[i];
    const int p = atomicAdd(&cur[d >> 8], 1);
    tmp[p] = ((u32)(d & 255) << 16) | (u32)src[i];
  }
}

// phase C: one block per 256-node bucket; derives per-node off[] (LDS histogram + scan),
// then scatters lst within the bucket's window.
__global__ void bucket_fill(const u32* __restrict__ t0, const int* __restrict__ ho0,
                            int n0, int* __restrict__ off0, int* __restrict__ l0,
                            const u32* __restrict__ t1, const int* __restrict__ ho1,
                            int n1, int* __restrict__ off1, int* __restrict__ l1,
                            int E, int nblk, int nbuckets) {
  const int sel = blockIdx.y;
  const u32* tmp = sel ? t1 : t0;
  const int* hoff = sel ? ho1 : ho0;
  const int n = sel ? n1 : n0;
  int* off = sel ? off1 : off0;
  int* lst = sel ? l1 : l0;
  const int b = blockIdx.x;
  const int node0 = b << 8;
  if (node0 >= n) return;
  const int nodes = (n - node0 < 256) ? (n - node0) : 256;
  const int base = hoff[b * nblk];
  const int bend = hoff[(b + 1) * nblk];
  const int t = threadIdx.x, lane = t & 63, w = t >> 6;
  __shared__ int cnt[256];
  __shared__ int wsum[4];
  cnt[t] = 0;
  __syncthreads();
  for (int i = base + t; i < bend; i += 256) atomicAdd(&cnt[tmp[i] >> 16], 1);
  __syncthreads();
  const int v = cnt[t];
  int inc = v;
#pragma unroll
  for (int d = 1; d < 64; d <<= 1) {
    int x = __shfl_up(inc, d, 64);
    if (lane >= d) inc += x;
  }
  if (lane == 63) wsum[w] = inc;
  __syncthreads();
  int wb = 0;
  for (int q = 0; q < w; ++q) wb += wsum[q];
  const int excl = base + (inc - v) + wb;
  __syncthreads();
  cnt[t] = excl;
  if (t < nodes) off[node0 + t] = excl;
  if (node0 + nodes == n && t == 0) off[n] = E;
  __syncthreads();
  for (int i = base + t; i < bend; i += 256) {
    const u32 pk = tmp[i];
    const int p = atomicAdd(&cnt[pk >> 16], 1);
    lst[p] = (int)(pk & 0xffffu);
  }
}

// one wave per destination node, half-wave per edge (2 edges/iter), uint4 (16B) loads,
// unroll 4 pairs -> 8 edges in flight. Both directions in one launch (blockIdx.y).
// [R6 version — best measured: ~104us, 3.9TB/s gather pattern ceiling (L2-miss-path bound)]
__global__ void seg_mean(const u16* __restrict__ f0, const int* __restrict__ o0,
                         const int* __restrict__ l0, u16* __restrict__ out0, int n0,
                         const u16* __restrict__ f1, const int* __restrict__ o1,
                         const int* __restrict__ l1, u16* __restrict__ out1, int n1) {
  const int sel = blockIdx.y;
  const u16* feat = sel ? f1 : f0;
  const int* off = sel ? o1 : o0;
  const int* lst = sel ? l1 : l0;
  u16* out = sel ? out1 : out0;
  const int ndst = sel ? n1 : n0;
  const int wid = threadIdx.x >> 6, lane = threadIdx.x & 63;
  const int node = blockIdx.x * 4 + wid;
  if (node >= ndst) return;
  const int s = off[node], e = off[node + 1];
  const int half = lane >> 5, hl = lane & 31;
  float a[8];
#pragma unroll
  for (int j = 0; j < 8; ++j) a[j] = 0.f;
  int i = s;
  for (; i + 8 <= e; i += 8) {
    const int q0 = lst[i + half], q1 = lst[i + 2 + half];
    const int q2 = lst[i + 4 + half], q3 = lst[i + 6 + half];
    const uint4 v0 = *reinterpret_cast<const uint4*>(feat + (size_t)q0 * NDIM + hl * 8);
    const uint4 v1 = *reinterpret_cast<const uint4*>(feat + (size_t)q1 * NDIM + hl * 8);
    const uint4 v2 = *reinterpret_cast<const uint4*>(feat + (size_t)q2 * NDIM + hl * 8);
    const uint4 v3 = *reinterpret_cast<const uint4*>(feat + (size_t)q3 * NDIM + hl * 8);
    const u32 w0[4] = {v0.x, v0.y, v0.z, v0.w};
    const u32 w1[4] = {v1.x, v1.y, v1.z, v1.w};
    const u32 w2[4] = {v2.x, v2.y, v2.z, v2.w};
    const u32 w3[4] = {v3.x, v3.y, v3.z, v3.w};
#pragma unroll
    for (int q = 0; q < 4; ++q) {
      a[2 * q] += bf2f((u16)(w0[q] & 0xffffu)) + bf2f((u16)(w1[q] & 0xffffu)) +
                  bf2f((u16)(w2[q] & 0xffffu)) + bf2f((u16)(w3[q] & 0xffffu));
      a[2 * q + 1] += bf2f((u16)(w0[q] >> 16)) + bf2f((u16)(w1[q] >> 16)) +
                      bf2f((u16)(w2[q] >> 16)) + bf2f((u16)(w3[q] >> 16));
    }
  }
  for (; i < e; i += 2) {
    if (i + half < e) {
      const int q = lst[i + half];
      const uint4 v = *reinterpret_cast<const uint4*>(feat + (size_t)q * NDIM + hl * 8);
      const u32 w[4] = {v.x, v.y, v.z, v.w};
#pragma unroll
      for (int t = 0; t < 4; ++t) {
        a[2 * t] += bf2f((u16)(w[t] & 0xffffu));
        a[2 * t + 1] += bf2f((u16)(w[t] >> 16));
      }
    }
  }
#pragma unroll
  for (int j = 0; j < 8; ++j) a[j] += __shfl_xor(a[j], 32, 64);
  if (half == 0) {
    const float inv = (e > s) ? 1.f / (float)(e - s) : 0.f;
    uint4 o;
    o.x = (u32)f2bf(a[0] * inv) | ((u32)f2bf(a[1] * inv) << 16);
    o.y = (u32)f2bf(a[2] * inv) | ((u32)f2bf(a[3] * inv) << 16);
    o.z = (u32)f2bf(a[4] * inv) | ((u32)f2bf(a[5] * inv) << 16);
    o.w = (u32)f2bf(a[6] * inv) | ((u32)f2bf(a[7] * inv) << 16);
    *reinterpret_cast<uint4*>(out + (size_t)node * NDIM + hl * 8) = o;
  }
}

// fused layer-2 epilogue: z = l2norm( mean_{src}(ymsg[src]) + yself[node] )
// COMPACT arrays: ymsg[n][128], yself[n][128]. quarter-wave per edge, 8 edges in flight.
__global__ void seg_out(const u16* __restrict__ ym0, const u16* __restrict__ ys0,
                        const int* __restrict__ o0, const int* __restrict__ l0,
                        float* __restrict__ z0, int n0,
                        const u16* __restrict__ ym1, const u16* __restrict__ ys1,
                        const int* __restrict__ o1, const int* __restrict__ l1,
                        float* __restrict__ z1, int n1) {
  const int sel = blockIdx.y;
  const u16* ymsg = sel ? ym1 : ym0;
  const u16* yself = sel ? ys1 : ys0;
  const int* off = sel ? o1 : o0;
  const int* lst = sel ? l1 : l0;
  float* zout = sel ? z1 : z0;
  const int ndst = sel ? n1 : n0;
  const int wid = threadIdx.x >> 6, lane = threadIdx.x & 63;
  const int node = blockIdx.x * 4 + wid;
  if (node >= ndst) return;
  const int s = off[node], e = off[node + 1];
  const int q = lane >> 4, ql = lane & 15;
  float a[8];
#pragma unroll
  for (int j = 0; j < 8; ++j) a[j] = 0.f;
  int i = s;
  for (; i + 8 <= e; i += 8) {
    const int r0 = lst[i + q], r1 = lst[i + 4 + q];
    const uint4 v0 = *reinterpret_cast<const uint4*>(ymsg + (size_t)r0 * 128 + ql * 8);
    const uint4 v1 = *reinterpret_cast<const uint4*>(ymsg + (size_t)r1 * 128 + ql * 8);
    const u32 w0[4] = {v0.x, v0.y, v0.z, v0.w};
    const u32 w1[4] = {v1.x, v1.y, v1.z, v1.w};
#pragma unroll
    for (int c = 0; c < 4; ++c) {
      a[2 * c] += bf2f((u16)(w0[c] & 0xffffu)) + bf2f((u16)(w1[c] & 0xffffu));
      a[2 * c + 1] += bf2f((u16)(w0[c] >> 16)) + bf2f((u16)(w1[c] >> 16));
    }
  }
  for (; i + 4 <= e; i += 4) {
    const int r = lst[i + q];
    const uint4 v = *reinterpret_cast<const uint4*>(ymsg + (size_t)r * 128 + ql * 8);
    const u32 w[4] = {v.x, v.y, v.z, v.w};
#pragma unroll
    for (int c = 0; c < 4; ++c) {
      a[2 * c] += bf2f((u16)(w[c] & 0xffffu));
      a[2 * c + 1] += bf2f((u16)(w[c] >> 16));
    }
  }
  if (i + q < e) {
    const int r = lst[i + q];
    const uint4 v = *reinterpret_cast<const uint4*>(ymsg + (size_t)r * 128 + ql * 8);
    const u32 w[4] = {v.x, v.y, v.z, v.w};
#pragma unroll
    for (int c = 0; c < 4; ++c) {
      a[2 * c] += bf2f((u16)(w[c] & 0xffffu));
      a[2 * c + 1] += bf2f((u16)(w[c] >> 16));
    }
  }
#pragma unroll
  for (int j = 0; j < 8; ++j) {
    a[j] += __shfl_xor(a[j], 16, 64);
    a[j] += __shfl_xor(a[j], 32, 64);
  }
  const float inv = (e > s) ? 1.f / (float)(e - s) : 0.f;
  const uint4 r = *reinterpret_cast<const uint4*>(yself + (size_t)node * 128 + ql * 8);
  const u32 rw[4] = {r.x, r.y, r.z, r.w};
  float z[8];
  float ss = 0.f;
#pragma unroll
  for (int c = 0; c < 4; ++c) {
    z[2 * c] = a[2 * c] * inv + bf2f((u16)(rw[c] & 0xffffu));
    z[2 * c + 1] = a[2 * c + 1] * inv + bf2f((u16)(rw[c] >> 16));
    ss += z[2 * c] * z[2 * c] + z[2 * c + 1] * z[2 * c + 1];
  }
#pragma unroll
  for (int d = 1; d < 16; d <<= 1) ss += __shfl_xor(ss, d, 64);
  const float sc = 1.f / fmaxf(sqrtf(ss), 1e-12f);
  if (q == 0) {
    float4 o0v, o1v;
    o0v.x = z[0] * sc; o0v.y = z[1] * sc; o0v.z = z[2] * sc; o0v.w = z[3] * sc;
    o1v.x = z[4] * sc; o1v.y = z[5] * sc; o1v.z = z[6] * sc; o1v.w = z[7] * sc;
    float* zp = zout + (size_t)node * 128 + ql * 8;
    *reinterpret_cast<float4*>(zp) = o0v;
    *reinterpret_cast<float4*>(zp + 4) = o1v;
  }
}

// Single-buffer 2-barrier GEMM with COALESCED+SWIZZLED staging, two instances via blockIdx.z.
// [R10 version — best measured. Double-buffer retried in R11: occupancy cliff, reverted.]
// C = A @ WT^T + bias. CAT: A = [Am | Ax] K-concat. SPLIT: bf16 out to msg[128]/self[128].
// Staging: 8 lanes cover one row's contiguous 128B (full-line requests); LDS linear
// [row][128B] with pre-swizzled global chunk (chunk^=row&7) + matching XOR on ds_read.
// XCD pair swizzle: both N-tiles of an M-tile land on the same XCD (A-panel L2 reuse).
template <bool RELU, bool CAT, int KT, bool SPLIT>
__global__ __launch_bounds__(256) void gemm2(
    const u16* __restrict__ Am0, const u16* __restrict__ Ax0,
    const u16* __restrict__ WT0, const float* __restrict__ bias0,
    u16* __restrict__ out0, u16* __restrict__ outs0, int M0,
    const u16* __restrict__ Am1, const u16* __restrict__ Ax1,
    const u16* __restrict__ WT1, const float* __restrict__ bias1,
    u16* __restrict__ out1, u16* __restrict__ outs1, int M1,
    int gx, int ldb, int ldo) {
  const int raw = blockIdx.x;
  const int xcd = raw & 7, seq = raw >> 3;
  const int ny = seq & 1;
  const int mt = (seq >> 1) * 8 + xcd;
  if (mt >= gx) return;
  const int sel = blockIdx.z;
  const u16* Am = sel ? Am1 : Am0;
  const u16* Ax = sel ? Ax1 : Ax0;
  const u16* WT = sel ? WT1 : WT0;
  const float* bias = sel ? bias1 : bias0;
  u16* out = sel ? out1 : out0;
  u16* outs = sel ? outs1 : outs0;
  const int M = sel ? M1 : M0;
  const int gm0 = mt * 128;
  if (gm0 >= M) return;
  const int n0 = ny * 128;

  __shared__ u16 As[8192];  // [row 0..127][64 k-elems = 128B], chunk-swizzled
  __shared__ u16 Bs[8192];
  const int tid = threadIdx.x;
  const int wid = tid >> 6, lane = tid & 63;
  const int wr = wid >> 1, wc = wid & 1;

  f32x4 acc[4][4];
  const f32x4 zz = {0.f, 0.f, 0.f, 0.f};
#pragma unroll
  for (int i = 0; i < 4; ++i)
#pragma unroll
    for (int j = 0; j < 4; ++j) acc[i][j] = zz;

  for (int kt = 0; kt < KT; ++kt) {
    const u16* Asrc = CAT ? ((kt < KT / 2) ? Am : Ax) : Am;
    const int koff = CAT ? ((kt & (KT / 2 - 1)) * 64) : kt * 64;
#pragma unroll
    for (int t = 0; t < 4; ++t) {
      const int f = wid * 256 + t * 64 + lane;       // 8 lanes per row, coalesced
      const int row = f >> 3;
      const int ch = (f & 7) ^ (row & 7);            // pre-swizzled global chunk
      int grow = gm0 + row; grow = (grow < M) ? grow : (M - 1);
      const u16* g = Asrc + (size_t)grow * NDIM + koff + ch * 8;
      u16* l = &As[(size_t)f * 8];
      __builtin_amdgcn_global_load_lds((const __attribute__((address_space(1))) void*)g,
                                       (__attribute__((address_space(3))) void*)l, 16, 0, 0);
    }
#pragma unroll
    for (int t = 0; t < 4; ++t) {
      const int f = wid * 256 + t * 64 + lane;
      const int n = f >> 3;
      const int ch = (f & 7) ^ (n & 7);
      const u16* g = WT + (size_t)(n0 + n) * ldb + kt * 64 + ch * 8;
      u16* l = &Bs[(size_t)f * 8];
      __builtin_amdgcn_global_load_lds((const __attribute__((address_space(1))) void*)g,
                                       (__attribute__((address_space(3))) void*)l, 16, 0, 0);
    }
    __syncthreads();
#pragma unroll
    for (int ks = 0; ks < 2; ++ks) {
      const int kc = ks * 4 + (lane >> 4);
      short8 a[4], b[4];
#pragma unroll
      for (int mtt = 0; mtt < 4; ++mtt) {
        const int R = wr * 64 + mtt * 16 + (lane & 15);
        a[mtt] = *reinterpret_cast<const short8*>(&As[(size_t)R * 64 + (kc ^ (R & 7)) * 8]);
      }
#pragma unroll
      for (int nt = 0; nt < 4; ++nt) {
        const int N = wc * 64 + nt * 16 + (lane & 15);
        b[nt] = *reinterpret_cast<const short8*>(&Bs[(size_t)N * 64 + (kc ^ (N & 7)) * 8]);
      }
#pragma unroll
      for (int mtt = 0; mtt < 4; ++mtt)
#pragma unroll
        for (int nt = 0; nt < 4; ++nt)
          acc[mtt][nt] = __builtin_amdgcn_mfma_f32_16x16x32_bf16(a[mtt], b[nt], acc[mtt][nt], 0, 0, 0);
    }
    __syncthreads();
  }

  const int rw = gm0 + wr * 64;
#pragma unroll
  for (int mtt = 0; mtt < 4; ++mtt) {
#pragma unroll
    for (int j = 0; j < 4; ++j) {
      int row = rw + mtt * 16 + ((lane >> 4) << 2) + j;
      if (row >= M) continue;
#pragma unroll
      for (int nt = 0; nt < 4; ++nt) {
        int col = n0 + wc * 64 + nt * 16 + (lane & 15);
        float v = acc[mtt][nt][j] + bias[col];
        if (RELU) v = fmaxf(v, 0.f);
        if constexpr (SPLIT) {
          if (col < 128) out[(size_t)row * 128 + col] = f2bf(v);
          else outs[(size_t)row * 128 + col - 128] = f2bf(v);
        } else {
          out[(size_t)row * ldo + col] = f2bf(v);
        }
      }
    }
  }
}

extern "C" void kernel_launch(void* const* d_in, const int* in_sizes, int n_in,
                              void* d_out, int out_size, void* d_ws, size_t ws_size,
                              hipStream_t stream) {
  const float* x_drug = (const float*)d_in[0];
  const float* x_prot = (const float*)d_in[1];
  const int* e_dp = (const int*)d_in[2];
  const int* e_pd = (const int*)d_in[3];
  const float* W1l_dp = (const float*)d_in[4];
  const float* W1r_dp = (const float*)d_in[5];
  const float* b1_dp = (const float*)d_in[6];
  const float* W1l_pd = (const float*)d_in[7];
  const float* W1r_pd = (const float*)d_in[8];
  const float* b1_pd = (const float*)d_in[9];
  const float* W2l_dp = (const float*)d_in[10];
  const float* W2r_dp = (const float*)d_in[11];
  const float* b2_dp = (const float*)d_in[12];
  const float* W2l_pd = (const float*)d_in[13];
  const float* W2r_pd = (const float*)d_in[14];
  const float* b2_pd = (const float*)d_in[15];

  const int E = in_sizes[2] / 2;
  const int ND = in_sizes[0] / NDIM;
  const int NP = in_sizes[1] / NDIM;

  const int* dp_src = e_dp;       // drug indices
  const int* dp_dst = e_dp + E;   // protein indices
  const int* pd_src = e_pd;       // protein indices
  const int* pd_dst = e_pd + E;   // drug indices

  char* ws = (char*)d_ws;
  size_t o = 0;
  auto alloc = [&](size_t bytes) -> void* {
    void* p = ws + o;
    o = (o + bytes + 255) & ~(size_t)255;
    return p;
  };
  u16* xd16 = (u16*)alloc((size_t)ND * NDIM * 2);
  u16* xp16 = (u16*)alloc((size_t)NP * NDIM * 2);
  u16* mp16 = (u16*)alloc((size_t)NP * NDIM * 2);  // means; reused as ymsg_p/yself_p
  u16* md16 = (u16*)alloc((size_t)ND * NDIM * 2);  // means; reused as ymsg_d/yself_d
  u16* hp16 = (u16*)alloc((size_t)NP * NDIM * 2);
  u16* hd16 = (u16*)alloc((size_t)ND * NDIM * 2);
  u16* wt1dp = (u16*)alloc((size_t)256 * KCAT * 2);
  u16* wt1pd = (u16*)alloc((size_t)256 * KCAT * 2);
  u16* wt2d = (u16*)alloc((size_t)256 * 256 * 2);  // [W2l_dp | W2r_pd] for drugs
  u16* wt2p = (u16*)alloc((size_t)256 * 256 * 2);  // [W2l_pd | W2r_dp] for proteins
  float* fbias_d = (float*)alloc(256 * 4);
  float* fbias_p = (float*)alloc(256 * 4);
  int* off_dp = (int*)alloc((size_t)(NP + 1) * 4);
  int* off_pd = (int*)alloc((size_t)(ND + 1) * 4);
  int* lst_dp = (int*)alloc((size_t)E * 4);
  int* lst_pd = (int*)alloc((size_t)E * 4);
  u32* tmp_dp = (u32*)alloc((size_t)E * 4);
  u32* tmp_pd = (u32*)alloc((size_t)E * 4);

  const int nmax = (NP > ND) ? NP : ND;
  const int nbuckets = (nmax + 255) >> 8;
  const int nblk = (E + EB - 1) / EB;
  const int nh = nbuckets * nblk;
  int* hist0 = (int*)alloc((size_t)nh * 4);
  int* hist1 = (int*)alloc((size_t)nh * 4);
  int* hoff0 = (int*)alloc((size_t)(nh + 1) * 4);
  int* hoff1 = (int*)alloc((size_t)(nh + 1) * 4);

  dim3 blk(256);

  // fused setup: cvt + W1/W2 prep + fbias + radix histogram, one launch
  const int n4d = ND * NDIM / 4, n4p = NP * NDIM / 4;
  const int tA = (n4d + n4p + 255) / 256;
  const int tB = tA + (2 * 256 * KCAT + 255) / 256;
  const int tC = tB + (2 * 256 * 256 + 255) / 256;
  const int tD = tC + 1;
  const int tTotal = tD + 2 * nblk;
  setup_all<<<tTotal, blk, 0, stream>>>(
      x_drug, n4d, x_prot, n4p, xd16, xp16,
      W1l_dp, W1r_dp, wt1dp, W1l_pd, W1r_pd, wt1pd,
      W2l_dp, W2r_pd, wt2d, W2l_pd, W2r_dp, wt2p,
      b2_pd, b2_dp, fbias_d, fbias_p,
      dp_dst, pd_dst, E, nblk, nbuckets, hist0, hist1,
      tA, tB, tC, tD);

  // single-kernel scan of both hist arrays
  scan_one<<<2, 1024, 0, stream>>>(hist0, hoff0, hist1, hoff1, nh);

  part_pass<<<dim3(nblk, 2), blk, 0, stream>>>(
      dp_src, dp_dst, tmp_dp, pd_src, pd_dst, tmp_pd, hoff0, hoff1, E, nblk, nbuckets);
  bucket_fill<<<dim3(nbuckets, 2), blk, 0, stream>>>(
      tmp_dp, hoff0, NP, off_dp, lst_dp, tmp_pd, hoff1, ND, off_pd, lst_pd, E, nblk, nbuckets);

  // layer 1: mean aggregation of raw features (both directions, one launch)
  seg_mean<<<dim3((nmax + 3) / 4, 2), blk, 0, stream>>>(
      xd16, off_dp, lst_dp, mp16, NP, xp16, off_pd, lst_pd, md16, ND);

  // GEMM grid: swizzled pairs, 8-aligned
  const int gx = (nmax + 127) / 128;
  const int gridx = ((gx + 7) / 8) * 16;  // mgrps*2*8

  // layer 1 GEMMs: h = relu([mean | x] @ W1cat + b)   (both node types via z)
  gemm2<true, true, 8, false><<<dim3(gridx, 1, 2), blk, 0, stream>>>(
      mp16, xp16, wt1dp, b1_dp, hp16, (u16*)nullptr, NP,
      md16, xd16, wt1pd, b1_pd, hd16, (u16*)nullptr, ND, gx, KCAT, 256);

  // layer 2 transform-first, COMPACT split outputs: ymsg[n][128], yself[n][128]
  u16* ymsg_d = md16;
  u16* yself_d = md16 + (size_t)ND * 128;
  u16* ymsg_p = mp16;
  u16* yself_p = mp16 + (size_t)NP * 128;
  gemm2<false, false, 4, true><<<dim3(gridx, 1, 2), blk, 0, stream>>>(
      hd16, hd16, wt2d, fbias_d, ymsg_d, yself_d, ND,
      hp16, hp16, wt2p, fbias_p, ymsg_p, yself_p, NP, gx, 256, 256);

  // fused: mean-gather of compact messages + self + L2 normalize -> d_out
  float* zd = (float*)d_out;
  float* zp = zd + (size_t)ND * 128;
  seg_out<<<dim3((nmax + 3) / 4, 2), blk, 0, stream>>>(
      ymsg_p, yself_d, off_pd, lst_pd, zd, ND, ymsg_d, yself_p, off_dp, lst_dp, zp, NP);
}

// Round 14
// 333.898 us; speedup vs baseline: 1.1647x; 1.1340x over previous
//
#include <hip/hip_runtime.h>

typedef unsigned short u16;
typedef unsigned int u32;
typedef unsigned char u8;
typedef __attribute__((ext_vector_type(8))) short short8;
typedef __attribute__((ext_vector_type(4))) float f32x4;

#define NDIM 256
#define KCAT 512
#define EB 8192      // edges per partition block
#define NBK_MAX 256  // max buckets (node>>8)

__device__ __forceinline__ float bf2f(u16 u) {
  union { u32 i; float f; } v; v.i = ((u32)u) << 16; return v.f;
}
__device__ __forceinline__ u16 f2bf(float f) {
  union { float f; u32 i; } v; v.f = f;
  u32 u = v.i;
  u32 r = (u + 0x7fffu + ((u >> 16) & 1u)) >> 16;  // RNE
  return (u16)r;
}
// pack 4 floats -> 4 fp8 e4m3 bytes (OCP on gfx950), HW RNE
__device__ __forceinline__ u32 pk4_fp8(float a, float b, float c, float d) {
  u32 p = __builtin_amdgcn_cvt_pk_fp8_f32(a, b, 0u, 0);
  p = __builtin_amdgcn_cvt_pk_fp8_f32(c, d, p, 1);
  return p;
}
__device__ __forceinline__ u8 f2fp8(float f) {
  return (u8)(__builtin_amdgcn_cvt_pk_fp8_f32(f, f, 0u, 0) & 0xffu);
}
// decode 4 fp8 bytes of w into o[0..3] — byte-select must be a LITERAL constant
__device__ __forceinline__ void fp8x4_acc(u32 w, float* o) {
  o[0] += __builtin_amdgcn_cvt_f32_fp8(w, 0);
  o[1] += __builtin_amdgcn_cvt_f32_fp8(w, 1);
  o[2] += __builtin_amdgcn_cvt_f32_fp8(w, 2);
  o[3] += __builtin_amdgcn_cvt_f32_fp8(w, 3);
}

// Horizontal fusion of all independent setup work (one launch):
//   [0,tA):    cvt fp32 -> bf16 AND fp8 of both feature tables
//   [tA,tB):   W1 transpose+K-concat (both directions)
//   [tB,tC):   W2 transpose+N-concat (both node types)
//   [tC,tD):   fused layer-2 bias vectors
//   [tD,...):  per-block LDS histogram of dst buckets (radix pass 1)
__global__ void setup_all(
    const float* __restrict__ xd, int n4d, const float* __restrict__ xp, int n4p,
    u16* __restrict__ xd16, u16* __restrict__ xp16,
    u32* __restrict__ xd8, u32* __restrict__ xp8,
    const float* __restrict__ W1l0, const float* __restrict__ W1r0, u16* __restrict__ WT10,
    const float* __restrict__ W1l1, const float* __restrict__ W1r1, u16* __restrict__ WT11,
    const float* __restrict__ W2l0, const float* __restrict__ W2r0, u16* __restrict__ WT20,
    const float* __restrict__ W2l1, const float* __restrict__ W2r1, u16* __restrict__ WT21,
    const float* __restrict__ b2d, const float* __restrict__ b2p,
    float* __restrict__ fd, float* __restrict__ fp,
    const int* __restrict__ dpd, const int* __restrict__ pdd, int E,
    int nblk, int nbuckets, int* __restrict__ h0, int* __restrict__ h1,
    int tA, int tB, int tC, int tD) {
  __shared__ int h[NBK_MAX];
  const int b = blockIdx.x;
  const int tid = threadIdx.x;
  if (b < tA) {
    int i = b * 256 + tid;
    const float* in; u16* out; u32* out8; int j;
    if (i < n4d) { in = xd; out = xd16; out8 = xd8; j = i; }
    else { j = i - n4d; if (j >= n4p) return; in = xp; out = xp16; out8 = xp8; }
    const float4 v = reinterpret_cast<const float4*>(in)[j];
    u32 lo = (u32)f2bf(v.x) | ((u32)f2bf(v.y) << 16);
    u32 hi = (u32)f2bf(v.z) | ((u32)f2bf(v.w) << 16);
    reinterpret_cast<uint2*>(out)[j] = make_uint2(lo, hi);
    out8[j] = pk4_fp8(v.x, v.y, v.z, v.w);
  } else if (b < tB) {
    int gidx = (b - tA) * 256 + tid;            // 2 x 131072
    const int sel = gidx >> 17;
    const int idx = gidx & 131071;
    const float* Wl = sel ? W1l1 : W1l0;
    const float* Wr = sel ? W1r1 : W1r0;
    u16* WT = sel ? WT11 : WT10;
    int n = idx >> 9, k = idx & 511;
    float v = (k < 256) ? Wl[k * 256 + n] : Wr[(k - 256) * 256 + n];
    WT[idx] = f2bf(v);
  } else if (b < tC) {
    int gidx = (b - tB) * 256 + tid;            // 2 x 65536
    const int sel = gidx >> 16;
    const int idx = gidx & 65535;
    const float* Wl = sel ? W2l1 : W2l0;
    const float* Wr = sel ? W2r1 : W2r0;
    u16* WT = sel ? WT21 : WT20;
    int n = idx >> 8, k = idx & 255;
    float v = (n < 128) ? Wl[k * 128 + n] : Wr[k * 128 + (n - 128)];
    WT[idx] = f2bf(v);
  } else if (b < tD) {
    fd[tid] = (tid < 128) ? 0.f : b2d[tid - 128];
    fp[tid] = (tid < 128) ? 0.f : b2p[tid - 128];
  } else {
    const int hb = b - tD;
    const int sel = (hb >= nblk);
    const int blk = sel ? hb - nblk : hb;
    const int* dst = sel ? pdd : dpd;
    int* hist = sel ? h1 : h0;
    for (int x = tid; x < nbuckets; x += 256) h[x] = 0;
    __syncthreads();
    const int e0 = blk * EB;
    const int e1 = (e0 + EB < E) ? (e0 + EB) : E;
    for (int i = e0 + tid; i < e1; i += 256) atomicAdd(&h[dst[i] >> 8], 1);
    __syncthreads();
    for (int x = tid; x < nbuckets; x += 256) hist[x * nblk + blk] = h[x];
  }
}

// single-kernel exclusive scan of both hist arrays (one block per direction, 1024 thr)
#define SCAN_PER 20
__global__ void scan_one(const int* __restrict__ h0, int* __restrict__ o0,
                         const int* __restrict__ h1, int* __restrict__ o1, int nh) {
  const int sel = blockIdx.x;
  const int* h = sel ? h1 : h0;
  int* off = sel ? o1 : o0;
  const int tid = threadIdx.x;  // 1024
  int v[SCAN_PER];
  int s = 0;
  const int i0 = tid * SCAN_PER;
#pragma unroll
  for (int j = 0; j < SCAN_PER; ++j) {
    int i = i0 + j;
    v[j] = (i < nh) ? h[i] : 0;
    s += v[j];
  }
  __shared__ int tile[1024];
  tile[tid] = s;
  __syncthreads();
  for (int d = 1; d < 1024; d <<= 1) {
    int t = (tid >= d) ? tile[tid - d] : 0;
    __syncthreads();
    tile[tid] += t;
    __syncthreads();
  }
  int run = tile[tid] - s;  // exclusive prefix of this thread's chunk
#pragma unroll
  for (int j = 0; j < SCAN_PER; ++j) {
    int i = i0 + j;
    run += v[j];
    if (i < nh) off[i + 1] = run;
  }
  if (tid == 0) off[0] = 0;
}

// radix-partition pass 2: LDS cursors = scanned (bucket,blk) offsets -> global slot directly.
__global__ void part_pass(const int* __restrict__ s0, const int* __restrict__ d0, u32* __restrict__ t0,
                          const int* __restrict__ s1, const int* __restrict__ d1, u32* __restrict__ t1,
                          const int* __restrict__ ho0, const int* __restrict__ ho1,
                          int E, int nblk, int nbuckets) {
  const int sel = blockIdx.y;
  const int* src = sel ? s1 : s0;
  const int* dst = sel ? d1 : d0;
  const int* hoff = sel ? ho1 : ho0;
  u32* tmp = sel ? t1 : t0;
  const int blk = blockIdx.x;
  __shared__ int cur[NBK_MAX];
  for (int b = threadIdx.x; b < nbuckets; b += 256) cur[b] = hoff[b * nblk + blk];
  __syncthreads();
  const int e0 = blk * EB;
  const int e1 = (e0 + EB < E) ? (e0 + EB) : E;
  for (int i = e0 + threadIdx.x; i < e1; i += 256) {
    const int d = dst[i];
    const int p = atomicAdd(&cur[d >> 8], 1);
    tmp[p] = ((u32)(d & 255) << 16) | (u32)src[i];
  }
}

// phase C: one block per 256-node bucket; derives per-node off[] (LDS histogram + scan),
// then scatters lst within the bucket's window.
__global__ void bucket_fill(const u32* __restrict__ t0, const int* __restrict__ ho0,
                            int n0, int* __restrict__ off0, int* __restrict__ l0,
                            const u32* __restrict__ t1, const int* __restrict__ ho1,
                            int n1, int* __restrict__ off1, int* __restrict__ l1,
                            int E, int nblk, int nbuckets) {
  const int sel = blockIdx.y;
  const u32* tmp = sel ? t1 : t0;
  const int* hoff = sel ? ho1 : ho0;
  const int n = sel ? n1 : n0;
  int* off = sel ? off1 : off0;
  int* lst = sel ? l1 : l0;
  const int b = blockIdx.x;
  const int node0 = b << 8;
  if (node0 >= n) return;
  const int nodes = (n - node0 < 256) ? (n - node0) : 256;
  const int base = hoff[b * nblk];
  const int bend = hoff[(b + 1) * nblk];
  const int t = threadIdx.x, lane = t & 63, w = t >> 6;
  __shared__ int cnt[256];
  __shared__ int wsum[4];
  cnt[t] = 0;
  __syncthreads();
  for (int i = base + t; i < bend; i += 256) atomicAdd(&cnt[tmp[i] >> 16], 1);
  __syncthreads();
  const int v = cnt[t];
  int inc = v;
#pragma unroll
  for (int d = 1; d < 64; d <<= 1) {
    int x = __shfl_up(inc, d, 64);
    if (lane >= d) inc += x;
  }
  if (lane == 63) wsum[w] = inc;
  __syncthreads();
  int wb = 0;
  for (int q = 0; q < w; ++q) wb += wsum[q];
  const int excl = base + (inc - v) + wb;
  __syncthreads();
  cnt[t] = excl;
  if (t < nodes) off[node0 + t] = excl;
  if (node0 + nodes == n && t == 0) off[n] = E;
  __syncthreads();
  for (int i = base + t; i < bend; i += 256) {
    const u32 pk = tmp[i];
    const int p = atomicAdd(&cnt[pk >> 16], 1);
    lst[p] = (int)(pk & 0xffffu);
  }
}

// fp8 mean-gather: feat is fp8-packed [node][64 u32] (256 B/row). One wave per dst node,
// half-wave per edge (uint2 = 8 fp8/lane), unroll 4 pairs -> 8 edges in flight.
// Output mean written bf16 [node][256]. Halves gather bytes vs bf16.
__global__ void seg_mean(const u32* __restrict__ f0, const int* __restrict__ o0,
                         const int* __restrict__ l0, u16* __restrict__ out0, int n0,
                         const u32* __restrict__ f1, const int* __restrict__ o1,
                         const int* __restrict__ l1, u16* __restrict__ out1, int n1) {
  const int sel = blockIdx.y;
  const u32* feat = sel ? f1 : f0;
  const int* off = sel ? o1 : o0;
  const int* lst = sel ? l1 : l0;
  u16* out = sel ? out1 : out0;
  const int ndst = sel ? n1 : n0;
  const int wid = threadIdx.x >> 6, lane = threadIdx.x & 63;
  const int node = blockIdx.x * 4 + wid;
  if (node >= ndst) return;
  const int s = off[node], e = off[node + 1];
  const int half = lane >> 5, hl = lane & 31;
  float a[8];
#pragma unroll
  for (int j = 0; j < 8; ++j) a[j] = 0.f;
  int i = s;
  for (; i + 8 <= e; i += 8) {
    const int q0 = lst[i + half], q1 = lst[i + 2 + half];
    const int q2 = lst[i + 4 + half], q3 = lst[i + 6 + half];
    const uint2 v0 = *reinterpret_cast<const uint2*>(feat + (size_t)q0 * 64 + hl * 2);
    const uint2 v1 = *reinterpret_cast<const uint2*>(feat + (size_t)q1 * 64 + hl * 2);
    const uint2 v2 = *reinterpret_cast<const uint2*>(feat + (size_t)q2 * 64 + hl * 2);
    const uint2 v3 = *reinterpret_cast<const uint2*>(feat + (size_t)q3 * 64 + hl * 2);
    fp8x4_acc(v0.x, a); fp8x4_acc(v0.y, a + 4);
    fp8x4_acc(v1.x, a); fp8x4_acc(v1.y, a + 4);
    fp8x4_acc(v2.x, a); fp8x4_acc(v2.y, a + 4);
    fp8x4_acc(v3.x, a); fp8x4_acc(v3.y, a + 4);
  }
  for (; i < e; i += 2) {
    if (i + half < e) {
      const int q = lst[i + half];
      const uint2 v = *reinterpret_cast<const uint2*>(feat + (size_t)q * 64 + hl * 2);
      fp8x4_acc(v.x, a);
      fp8x4_acc(v.y, a + 4);
    }
  }
#pragma unroll
  for (int j = 0; j < 8; ++j) a[j] += __shfl_xor(a[j], 32, 64);
  if (half == 0) {
    const float inv = (e > s) ? 1.f / (float)(e - s) : 0.f;
    uint4 o;
    o.x = (u32)f2bf(a[0] * inv) | ((u32)f2bf(a[1] * inv) << 16);
    o.y = (u32)f2bf(a[2] * inv) | ((u32)f2bf(a[3] * inv) << 16);
    o.z = (u32)f2bf(a[4] * inv) | ((u32)f2bf(a[5] * inv) << 16);
    o.w = (u32)f2bf(a[6] * inv) | ((u32)f2bf(a[7] * inv) << 16);
    *reinterpret_cast<uint4*>(out + (size_t)node * NDIM + hl * 8) = o;
  }
}

// fused layer-2 epilogue: z = l2norm( mean_{src}(ymsg[src]) + yself[node] )
// ymsg is fp8-packed [n][32 u32] (128 B/row); yself bf16 [n][128].
// quarter-wave per edge (uint2 = 8 fp8/lane), 8 edges in flight.
__global__ void seg_out(const u32* __restrict__ ym0, const u16* __restrict__ ys0,
                        const int* __restrict__ o0, const int* __restrict__ l0,
                        float* __restrict__ z0, int n0,
                        const u32* __restrict__ ym1, const u16* __restrict__ ys1,
                        const int* __restrict__ o1, const int* __restrict__ l1,
                        float* __restrict__ z1, int n1) {
  const int sel = blockIdx.y;
  const u32* ymsg = sel ? ym1 : ym0;
  const u16* yself = sel ? ys1 : ys0;
  const int* off = sel ? o1 : o0;
  const int* lst = sel ? l1 : l0;
  float* zout = sel ? z1 : z0;
  const int ndst = sel ? n1 : n0;
  const int wid = threadIdx.x >> 6, lane = threadIdx.x & 63;
  const int node = blockIdx.x * 4 + wid;
  if (node >= ndst) return;
  const int s = off[node], e = off[node + 1];
  const int q = lane >> 4, ql = lane & 15;
  float a[8];
#pragma unroll
  for (int j = 0; j < 8; ++j) a[j] = 0.f;
  int i = s;
  for (; i + 8 <= e; i += 8) {
    const int r0 = lst[i + q], r1 = lst[i + 4 + q];
    const uint2 v0 = *reinterpret_cast<const uint2*>(ymsg + (size_t)r0 * 32 + ql * 2);
    const uint2 v1 = *reinterpret_cast<const uint2*>(ymsg + (size_t)r1 * 32 + ql * 2);
    fp8x4_acc(v0.x, a); fp8x4_acc(v0.y, a + 4);
    fp8x4_acc(v1.x, a); fp8x4_acc(v1.y, a + 4);
  }
  for (; i + 4 <= e; i += 4) {
    const int r = lst[i + q];
    const uint2 v = *reinterpret_cast<const uint2*>(ymsg + (size_t)r * 32 + ql * 2);
    fp8x4_acc(v.x, a);
    fp8x4_acc(v.y, a + 4);
  }
  if (i + q < e) {
    const int r = lst[i + q];
    const uint2 v = *reinterpret_cast<const uint2*>(ymsg + (size_t)r * 32 + ql * 2);
    fp8x4_acc(v.x, a);
    fp8x4_acc(v.y, a + 4);
  }
#pragma unroll
  for (int j = 0; j < 8; ++j) {
    a[j] += __shfl_xor(a[j], 16, 64);
    a[j] += __shfl_xor(a[j], 32, 64);
  }
  const float inv = (e > s) ? 1.f / (float)(e - s) : 0.f;
  const uint4 r = *reinterpret_cast<const uint4*>(yself + (size_t)node * 128 + ql * 8);
  const u32 rw[4] = {r.x, r.y, r.z, r.w};
  float z[8];
  float ss = 0.f;
#pragma unroll
  for (int c = 0; c < 4; ++c) {
    z[2 * c] = a[2 * c] * inv + bf2f((u16)(rw[c] & 0xffffu));
    z[2 * c + 1] = a[2 * c + 1] * inv + bf2f((u16)(rw[c] >> 16));
    ss += z[2 * c] * z[2 * c] + z[2 * c + 1] * z[2 * c + 1];
  }
#pragma unroll
  for (int d = 1; d < 16; d <<= 1) ss += __shfl_xor(ss, d, 64);
  const float sc = 1.f / fmaxf(sqrtf(ss), 1e-12f);
  if (q == 0) {
    float4 o0v, o1v;
    o0v.x = z[0] * sc; o0v.y = z[1] * sc; o0v.z = z[2] * sc; o0v.w = z[3] * sc;
    o1v.x = z[4] * sc; o1v.y = z[5] * sc; o1v.z = z[6] * sc; o1v.w = z[7] * sc;
    float* zp = zout + (size_t)node * 128 + ql * 8;
    *reinterpret_cast<float4*>(zp) = o0v;
    *reinterpret_cast<float4*>(zp + 4) = o1v;
  }
}

// Single-buffer 2-barrier GEMM with COALESCED+SWIZZLED staging, two instances via blockIdx.z.
// [R10 structure — best measured.] C = A @ WT^T + bias.
// CAT: A = [Am | Ax] K-concat. SPLIT: msg cols -> fp8 [n][128], self cols -> bf16 [n][128].
template <bool RELU, bool CAT, int KT, bool SPLIT>
__global__ __launch_bounds__(256) void gemm2(
    const u16* __restrict__ Am0, const u16* __restrict__ Ax0,
    const u16* __restrict__ WT0, const float* __restrict__ bias0,
    u16* __restrict__ out0, u8* __restrict__ out8_0, int M0,
    const u16* __restrict__ Am1, const u16* __restrict__ Ax1,
    const u16* __restrict__ WT1, const float* __restrict__ bias1,
    u16* __restrict__ out1, u8* __restrict__ out8_1, int M1,
    int gx, int ldb, int ldo) {
  const int raw = blockIdx.x;
  const int xcd = raw & 7, seq = raw >> 3;
  const int ny = seq & 1;
  const int mt = (seq >> 1) * 8 + xcd;
  if (mt >= gx) return;
  const int sel = blockIdx.z;
  const u16* Am = sel ? Am1 : Am0;
  const u16* Ax = sel ? Ax1 : Ax0;
  const u16* WT = sel ? WT1 : WT0;
  const float* bias = sel ? bias1 : bias0;
  u16* out = sel ? out1 : out0;
  u8* out8 = sel ? out8_1 : out8_0;
  const int M = sel ? M1 : M0;
  const int gm0 = mt * 128;
  if (gm0 >= M) return;
  const int n0 = ny * 128;

  __shared__ u16 As[8192];  // [row 0..127][64 k-elems = 128B], chunk-swizzled
  __shared__ u16 Bs[8192];
  const int tid = threadIdx.x;
  const int wid = tid >> 6, lane = tid & 63;
  const int wr = wid >> 1, wc = wid & 1;

  f32x4 acc[4][4];
  const f32x4 zz = {0.f, 0.f, 0.f, 0.f};
#pragma unroll
  for (int i = 0; i < 4; ++i)
#pragma unroll
    for (int j = 0; j < 4; ++j) acc[i][j] = zz;

  for (int kt = 0; kt < KT; ++kt) {
    const u16* Asrc = CAT ? ((kt < KT / 2) ? Am : Ax) : Am;
    const int koff = CAT ? ((kt & (KT / 2 - 1)) * 64) : kt * 64;
#pragma unroll
    for (int t = 0; t < 4; ++t) {
      const int f = wid * 256 + t * 64 + lane;       // 8 lanes per row, coalesced
      const int row = f >> 3;
      const int ch = (f & 7) ^ (row & 7);            // pre-swizzled global chunk
      int grow = gm0 + row; grow = (grow < M) ? grow : (M - 1);
      const u16* g = Asrc + (size_t)grow * NDIM + koff + ch * 8;
      u16* l = &As[(size_t)f * 8];
      __builtin_amdgcn_global_load_lds((const __attribute__((address_space(1))) void*)g,
                                       (__attribute__((address_space(3))) void*)l, 16, 0, 0);
    }
#pragma unroll
    for (int t = 0; t < 4; ++t) {
      const int f = wid * 256 + t * 64 + lane;
      const int n = f >> 3;
      const int ch = (f & 7) ^ (n & 7);
      const u16* g = WT + (size_t)(n0 + n) * ldb + kt * 64 + ch * 8;
      u16* l = &Bs[(size_t)f * 8];
      __builtin_amdgcn_global_load_lds((const __attribute__((address_space(1))) void*)g,
                                       (__attribute__((address_space(3))) void*)l, 16, 0, 0);
    }
    __syncthreads();
#pragma unroll
    for (int ks = 0; ks < 2; ++ks) {
      const int kc = ks * 4 + (lane >> 4);
      short8 a[4], b[4];
#pragma unroll
      for (int mtt = 0; mtt < 4; ++mtt) {
        const int R = wr * 64 + mtt * 16 + (lane & 15);
        a[mtt] = *reinterpret_cast<const short8*>(&As[(size_t)R * 64 + (kc ^ (R & 7)) * 8]);
      }
#pragma unroll
      for (int nt = 0; nt < 4; ++nt) {
        const int N = wc * 64 + nt * 16 + (lane & 15);
        b[nt] = *reinterpret_cast<const short8*>(&Bs[(size_t)N * 64 + (kc ^ (N & 7)) * 8]);
      }
#pragma unroll
      for (int mtt = 0; mtt < 4; ++mtt)
#pragma unroll
        for (int nt = 0; nt < 4; ++nt)
          acc[mtt][nt] = __builtin_amdgcn_mfma_f32_16x16x32_bf16(a[mtt], b[nt], acc[mtt][nt], 0, 0, 0);
    }
    __syncthreads();
  }

  const int rw = gm0 + wr * 64;
#pragma unroll
  for (int mtt = 0; mtt < 4; ++mtt) {
#pragma unroll
    for (int j = 0; j < 4; ++j) {
      int row = rw + mtt * 16 + ((lane >> 4) << 2) + j;
      if (row >= M) continue;
#pragma unroll
      for (int nt = 0; nt < 4; ++nt) {
        int col = n0 + wc * 64 + nt * 16 + (lane & 15);
        float v = acc[mtt][nt][j] + bias[col];
        if (RELU) v = fmaxf(v, 0.f);
        if constexpr (SPLIT) {
          if (col < 128) out8[(size_t)row * 128 + col] = f2fp8(v);
          else out[(size_t)row * 128 + col - 128] = f2bf(v);
        } else {
          out[(size_t)row * ldo + col] = f2bf(v);
        }
      }
    }
  }
}

extern "C" void kernel_launch(void* const* d_in, const int* in_sizes, int n_in,
                              void* d_out, int out_size, void* d_ws, size_t ws_size,
                              hipStream_t stream) {
  const float* x_drug = (const float*)d_in[0];
  const float* x_prot = (const float*)d_in[1];
  const int* e_dp = (const int*)d_in[2];
  const int* e_pd = (const int*)d_in[3];
  const float* W1l_dp = (const float*)d_in[4];
  const float* W1r_dp = (const float*)d_in[5];
  const float* b1_dp = (const float*)d_in[6];
  const float* W1l_pd = (const float*)d_in[7];
  const float* W1r_pd = (const float*)d_in[8];
  const float* b1_pd = (const float*)d_in[9];
  const float* W2l_dp = (const float*)d_in[10];
  const float* W2r_dp = (const float*)d_in[11];
  const float* b2_dp = (const float*)d_in[12];
  const float* W2l_pd = (const float*)d_in[13];
  const float* W2r_pd = (const float*)d_in[14];
  const float* b2_pd = (const float*)d_in[15];

  const int E = in_sizes[2] / 2;
  const int ND = in_sizes[0] / NDIM;
  const int NP = in_sizes[1] / NDIM;

  const int* dp_src = e_dp;       // drug indices
  const int* dp_dst = e_dp + E;   // protein indices
  const int* pd_src = e_pd;       // protein indices
  const int* pd_dst = e_pd + E;   // drug indices

  char* ws = (char*)d_ws;
  size_t o = 0;
  auto alloc = [&](size_t bytes) -> void* {
    void* p = ws + o;
    o = (o + bytes + 255) & ~(size_t)255;
    return p;
  };
  u16* xd16 = (u16*)alloc((size_t)ND * NDIM * 2);
  u16* xp16 = (u16*)alloc((size_t)NP * NDIM * 2);
  u32* xd8 = (u32*)alloc((size_t)ND * 64 * 4);     // fp8-packed x (drug)
  u32* xp8 = (u32*)alloc((size_t)NP * 64 * 4);     // fp8-packed x (protein)
  u16* mp16 = (u16*)alloc((size_t)NP * NDIM * 2);  // means; reused as yself_p
  u16* md16 = (u16*)alloc((size_t)ND * NDIM * 2);  // means; reused as yself_d
  u16* hp16 = (u16*)alloc((size_t)NP * NDIM * 2);
  u16* hd16 = (u16*)alloc((size_t)ND * NDIM * 2);
  u32* ymd8 = (u32*)alloc((size_t)ND * 32 * 4);    // fp8-packed layer-2 messages (drug)
  u32* ymp8 = (u32*)alloc((size_t)NP * 32 * 4);    // fp8-packed layer-2 messages (protein)
  u16* wt1dp = (u16*)alloc((size_t)256 * KCAT * 2);
  u16* wt1pd = (u16*)alloc((size_t)256 * KCAT * 2);
  u16* wt2d = (u16*)alloc((size_t)256 * 256 * 2);  // [W2l_dp | W2r_pd] for drugs
  u16* wt2p = (u16*)alloc((size_t)256 * 256 * 2);  // [W2l_pd | W2r_dp] for proteins
  float* fbias_d = (float*)alloc(256 * 4);
  float* fbias_p = (float*)alloc(256 * 4);
  int* off_dp = (int*)alloc((size_t)(NP + 1) * 4);
  int* off_pd = (int*)alloc((size_t)(ND + 1) * 4);
  int* lst_dp = (int*)alloc((size_t)E * 4);
  int* lst_pd = (int*)alloc((size_t)E * 4);
  u32* tmp_dp = (u32*)alloc((size_t)E * 4);
  u32* tmp_pd = (u32*)alloc((size_t)E * 4);

  const int nmax = (NP > ND) ? NP : ND;
  const int nbuckets = (nmax + 255) >> 8;
  const int nblk = (E + EB - 1) / EB;
  const int nh = nbuckets * nblk;
  int* hist0 = (int*)alloc((size_t)nh * 4);
  int* hist1 = (int*)alloc((size_t)nh * 4);
  int* hoff0 = (int*)alloc((size_t)(nh + 1) * 4);
  int* hoff1 = (int*)alloc((size_t)(nh + 1) * 4);

  dim3 blk(256);

  // fused setup: cvt (bf16 + fp8) + W1/W2 prep + fbias + radix histogram, one launch
  const int n4d = ND * NDIM / 4, n4p = NP * NDIM / 4;
  const int tA = (n4d + n4p + 255) / 256;
  const int tB = tA + (2 * 256 * KCAT + 255) / 256;
  const int tC = tB + (2 * 256 * 256 + 255) / 256;
  const int tD = tC + 1;
  const int tTotal = tD + 2 * nblk;
  setup_all<<<tTotal, blk, 0, stream>>>(
      x_drug, n4d, x_prot, n4p, xd16, xp16, xd8, xp8,
      W1l_dp, W1r_dp, wt1dp, W1l_pd, W1r_pd, wt1pd,
      W2l_dp, W2r_pd, wt2d, W2l_pd, W2r_dp, wt2p,
      b2_pd, b2_dp, fbias_d, fbias_p,
      dp_dst, pd_dst, E, nblk, nbuckets, hist0, hist1,
      tA, tB, tC, tD);

  // single-kernel scan of both hist arrays
  scan_one<<<2, 1024, 0, stream>>>(hist0, hoff0, hist1, hoff1, nh);

  part_pass<<<dim3(nblk, 2), blk, 0, stream>>>(
      dp_src, dp_dst, tmp_dp, pd_src, pd_dst, tmp_pd, hoff0, hoff1, E, nblk, nbuckets);
  bucket_fill<<<dim3(nbuckets, 2), blk, 0, stream>>>(
      tmp_dp, hoff0, NP, off_dp, lst_dp, tmp_pd, hoff1, ND, off_pd, lst_pd, E, nblk, nbuckets);

  // layer 1: fp8 mean aggregation of raw features (both directions, one launch)
  seg_mean<<<dim3((nmax + 3) / 4, 2), blk, 0, stream>>>(
      xd8, off_dp, lst_dp, mp16, NP, xp8, off_pd, lst_pd, md16, ND);

  // GEMM grid: swizzled pairs, 8-aligned
  const int gx = (nmax + 127) / 128;
  const int gridx = ((gx + 7) / 8) * 16;  // mgrps*2*8

  // layer 1 GEMMs: h = relu([mean | x] @ W1cat + b)   (both node types via z)
  gemm2<true, true, 8, false><<<dim3(gridx, 1, 2), blk, 0, stream>>>(
      mp16, xp16, wt1dp, b1_dp, hp16, (u8*)nullptr, NP,
      md16, xd16, wt1pd, b1_pd, hd16, (u8*)nullptr, ND, gx, KCAT, 256);

  // layer 2 transform-first, split outputs: ymsg fp8 [n][128], yself bf16 [n][128]
  u16* yself_d = md16;  // reuse dead mean buffers
  u16* yself_p = mp16;
  gemm2<false, false, 4, true><<<dim3(gridx, 1, 2), blk, 0, stream>>>(
      hd16, hd16, wt2d, fbias_d, yself_d, (u8*)ymd8, ND,
      hp16, hp16, wt2p, fbias_p, yself_p, (u8*)ymp8, NP, gx, 256, 256);

  // fused: fp8 mean-gather of messages + self + L2 normalize -> d_out
  float* zd = (float*)d_out;
  float* zp = zd + (size_t)ND * 128;
  seg_out<<<dim3((nmax + 3) / 4, 2), blk, 0, stream>>>(
      ymp8, yself_d, off_pd, lst_pd, zd, ND, ymd8, yself_p, off_dp, lst_dp, zp, NP);
}

// Round 15
// 330.207 us; speedup vs baseline: 1.1778x; 1.0112x over previous
//
#include <hip/hip_runtime.h>

typedef unsigned short u16;
typedef unsigned int u32;
typedef unsigned char u8;
typedef __attribute__((ext_vector_type(8))) short short8;
typedef __attribute__((ext_vector_type(4))) float f32x4;
typedef __attribute__((ext_vector_type(2))) float f32x2;

#define NDIM 256
#define KCAT 512
#define EB 8192      // edges per partition block
#define NBK_MAX 256  // max buckets (node>>8)

__device__ __forceinline__ float bf2f(u16 u) {
  union { u32 i; float f; } v; v.i = ((u32)u) << 16; return v.f;
}
__device__ __forceinline__ u16 f2bf(float f) {
  union { float f; u32 i; } v; v.f = f;
  u32 u = v.i;
  u32 r = (u + 0x7fffu + ((u >> 16) & 1u)) >> 16;  // RNE
  return (u16)r;
}
// pack 4 floats -> 4 fp8 e4m3 bytes (OCP on gfx950), HW RNE
__device__ __forceinline__ u32 pk4_fp8(float a, float b, float c, float d) {
  u32 p = __builtin_amdgcn_cvt_pk_fp8_f32(a, b, 0u, 0);
  p = __builtin_amdgcn_cvt_pk_fp8_f32(c, d, p, 1);
  return p;
}
__device__ __forceinline__ u8 f2fp8(float f) {
  return (u8)(__builtin_amdgcn_cvt_pk_fp8_f32(f, f, 0u, 0) & 0xffu);
}
// packed fp8 pair decode: bytes [0,1] (lo) or [2,3] (hi) of w -> float2, one VALU op
#if __has_builtin(__builtin_amdgcn_cvt_pk_f32_fp8)
__device__ __forceinline__ f32x2 fp8pk_lo(u32 w) { return __builtin_amdgcn_cvt_pk_f32_fp8(w, false); }
__device__ __forceinline__ f32x2 fp8pk_hi(u32 w) { return __builtin_amdgcn_cvt_pk_f32_fp8(w, true); }
#else
__device__ __forceinline__ f32x2 fp8pk_lo(u32 w) {
  f32x2 r; r.x = __builtin_amdgcn_cvt_f32_fp8(w, 0); r.y = __builtin_amdgcn_cvt_f32_fp8(w, 1); return r;
}
__device__ __forceinline__ f32x2 fp8pk_hi(u32 w) {
  f32x2 r; r.x = __builtin_amdgcn_cvt_f32_fp8(w, 2); r.y = __builtin_amdgcn_cvt_f32_fp8(w, 3); return r;
}
#endif
// accumulate one u32 (4 fp8, elems 4w..4w+3) into a[0..1] (f32x2 pairs)
__device__ __forceinline__ void fp8w_acc(u32 w, f32x2* a) {
  a[0] += fp8pk_lo(w);
  a[1] += fp8pk_hi(w);
}

// Horizontal fusion of all independent setup work (one launch):
//   [0,tA):    cvt fp32 -> bf16 AND fp8 of both feature tables
//   [tA,tB):   W1 transpose+K-concat (both directions)
//   [tB,tC):   W2 transpose+N-concat (both node types)
//   [tC,tD):   fused layer-2 bias vectors
//   [tD,...):  per-block LDS histogram of dst buckets (radix pass 1)
__global__ void setup_all(
    const float* __restrict__ xd, int n4d, const float* __restrict__ xp, int n4p,
    u16* __restrict__ xd16, u16* __restrict__ xp16,
    u32* __restrict__ xd8, u32* __restrict__ xp8,
    const float* __restrict__ W1l0, const float* __restrict__ W1r0, u16* __restrict__ WT10,
    const float* __restrict__ W1l1, const float* __restrict__ W1r1, u16* __restrict__ WT11,
    const float* __restrict__ W2l0, const float* __restrict__ W2r0, u16* __restrict__ WT20,
    const float* __restrict__ W2l1, const float* __restrict__ W2r1, u16* __restrict__ WT21,
    const float* __restrict__ b2d, const float* __restrict__ b2p,
    float* __restrict__ fd, float* __restrict__ fp,
    const int* __restrict__ dpd, const int* __restrict__ pdd, int E,
    int nblk, int nbuckets, int* __restrict__ h0, int* __restrict__ h1,
    int tA, int tB, int tC, int tD) {
  __shared__ int h[NBK_MAX];
  const int b = blockIdx.x;
  const int tid = threadIdx.x;
  if (b < tA) {
    int i = b * 256 + tid;
    const float* in; u16* out; u32* out8; int j;
    if (i < n4d) { in = xd; out = xd16; out8 = xd8; j = i; }
    else { j = i - n4d; if (j >= n4p) return; in = xp; out = xp16; out8 = xp8; }
    const float4 v = reinterpret_cast<const float4*>(in)[j];
    u32 lo = (u32)f2bf(v.x) | ((u32)f2bf(v.y) << 16);
    u32 hi = (u32)f2bf(v.z) | ((u32)f2bf(v.w) << 16);
    reinterpret_cast<uint2*>(out)[j] = make_uint2(lo, hi);
    out8[j] = pk4_fp8(v.x, v.y, v.z, v.w);
  } else if (b < tB) {
    int gidx = (b - tA) * 256 + tid;            // 2 x 131072
    const int sel = gidx >> 17;
    const int idx = gidx & 131071;
    const float* Wl = sel ? W1l1 : W1l0;
    const float* Wr = sel ? W1r1 : W1r0;
    u16* WT = sel ? WT11 : WT10;
    int n = idx >> 9, k = idx & 511;
    float v = (k < 256) ? Wl[k * 256 + n] : Wr[(k - 256) * 256 + n];
    WT[idx] = f2bf(v);
  } else if (b < tC) {
    int gidx = (b - tB) * 256 + tid;            // 2 x 65536
    const int sel = gidx >> 16;
    const int idx = gidx & 65535;
    const float* Wl = sel ? W2l1 : W2l0;
    const float* Wr = sel ? W2r1 : W2r0;
    u16* WT = sel ? WT21 : WT20;
    int n = idx >> 8, k = idx & 255;
    float v = (n < 128) ? Wl[k * 128 + n] : Wr[k * 128 + (n - 128)];
    WT[idx] = f2bf(v);
  } else if (b < tD) {
    fd[tid] = (tid < 128) ? 0.f : b2d[tid - 128];
    fp[tid] = (tid < 128) ? 0.f : b2p[tid - 128];
  } else {
    const int hb = b - tD;
    const int sel = (hb >= nblk);
    const int blk = sel ? hb - nblk : hb;
    const int* dst = sel ? pdd : dpd;
    int* hist = sel ? h1 : h0;
    for (int x = tid; x < nbuckets; x += 256) h[x] = 0;
    __syncthreads();
    const int e0 = blk * EB;
    const int e1 = (e0 + EB < E) ? (e0 + EB) : E;
    for (int i = e0 + tid; i < e1; i += 256) atomicAdd(&h[dst[i] >> 8], 1);
    __syncthreads();
    for (int x = tid; x < nbuckets; x += 256) hist[x * nblk + blk] = h[x];
  }
}

// single-kernel exclusive scan of both hist arrays (one block per direction, 1024 thr)
#define SCAN_PER 20
__global__ void scan_one(const int* __restrict__ h0, int* __restrict__ o0,
                         const int* __restrict__ h1, int* __restrict__ o1, int nh) {
  const int sel = blockIdx.x;
  const int* h = sel ? h1 : h0;
  int* off = sel ? o1 : o0;
  const int tid = threadIdx.x;  // 1024
  int v[SCAN_PER];
  int s = 0;
  const int i0 = tid * SCAN_PER;
#pragma unroll
  for (int j = 0; j < SCAN_PER; ++j) {
    int i = i0 + j;
    v[j] = (i < nh) ? h[i] : 0;
    s += v[j];
  }
  __shared__ int tile[1024];
  tile[tid] = s;
  __syncthreads();
  for (int d = 1; d < 1024; d <<= 1) {
    int t = (tid >= d) ? tile[tid - d] : 0;
    __syncthreads();
    tile[tid] += t;
    __syncthreads();
  }
  int run = tile[tid] - s;  // exclusive prefix of this thread's chunk
#pragma unroll
  for (int j = 0; j < SCAN_PER; ++j) {
    int i = i0 + j;
    run += v[j];
    if (i < nh) off[i + 1] = run;
  }
  if (tid == 0) off[0] = 0;
}

// radix-partition pass 2: LDS cursors = scanned (bucket,blk) offsets -> global slot directly.
__global__ void part_pass(const int* __restrict__ s0, const int* __restrict__ d0, u32* __restrict__ t0,
                          const int* __restrict__ s1, const int* __restrict__ d1, u32* __restrict__ t1,
                          const int* __restrict__ ho0, const int* __restrict__ ho1,
                          int E, int nblk, int nbuckets) {
  const int sel = blockIdx.y;
  const int* src = sel ? s1 : s0;
  const int* dst = sel ? d1 : d0;
  const int* hoff = sel ? ho1 : ho0;
  u32* tmp = sel ? t1 : t0;
  const int blk = blockIdx.x;
  __shared__ int cur[NBK_MAX];
  for (int b = threadIdx.x; b < nbuckets; b += 256) cur[b] = hoff[b * nblk + blk];
  __syncthreads();
  const int e0 = blk * EB;
  const int e1 = (e0 + EB < E) ? (e0 + EB) : E;
  for (int i = e0 + threadIdx.x; i < e1; i += 256) {
    const int d = dst[i];
    const int p = atomicAdd(&cur[d >> 8], 1);
    tmp[p] = ((u32)(d & 255) << 16) | (u32)src[i];
  }
}

// phase C: one block per 256-node bucket; derives per-node off[] (LDS histogram + scan),
// then scatters lst within the bucket's window.
__global__ void bucket_fill(const u32* __restrict__ t0, const int* __restrict__ ho0,
                            int n0, int* __restrict__ off0, int* __restrict__ l0,
                            const u32* __restrict__ t1, const int* __restrict__ ho1,
                            int n1, int* __restrict__ off1, int* __restrict__ l1,
                            int E, int nblk, int nbuckets) {
  const int sel = blockIdx.y;
  const u32* tmp = sel ? t1 : t0;
  const int* hoff = sel ? ho1 : ho0;
  const int n = sel ? n1 : n0;
  int* off = sel ? off1 : off0;
  int* lst = sel ? l1 : l0;
  const int b = blockIdx.x;
  const int node0 = b << 8;
  if (node0 >= n) return;
  const int nodes = (n - node0 < 256) ? (n - node0) : 256;
  const int base = hoff[b * nblk];
  const int bend = hoff[(b + 1) * nblk];
  const int t = threadIdx.x, lane = t & 63, w = t >> 6;
  __shared__ int cnt[256];
  __shared__ int wsum[4];
  cnt[t] = 0;
  __syncthreads();
  for (int i = base + t; i < bend; i += 256) atomicAdd(&cnt[tmp[i] >> 16], 1);
  __syncthreads();
  const int v = cnt[t];
  int inc = v;
#pragma unroll
  for (int d = 1; d < 64; d <<= 1) {
    int x = __shfl_up(inc, d, 64);
    if (lane >= d) inc += x;
  }
  if (lane == 63) wsum[w] = inc;
  __syncthreads();
  int wb = 0;
  for (int q = 0; q < w; ++q) wb += wsum[q];
  const int excl = base + (inc - v) + wb;
  __syncthreads();
  cnt[t] = excl;
  if (t < nodes) off[node0 + t] = excl;
  if (node0 + nodes == n && t == 0) off[n] = E;
  __syncthreads();
  for (int i = base + t; i < bend; i += 256) {
    const u32 pk = tmp[i];
    const int p = atomicAdd(&cnt[pk >> 16], 1);
    lst[p] = (int)(pk & 0xffffu);
  }
}

// fp8 mean-gather with PACKED decode: feat fp8-packed [node][64 u32]. One wave per dst node,
// half-wave per edge (uint2 = 8 fp8/lane), 8 edges in flight. f32x2 accumulators ->
// v_cvt_pk_f32_fp8 + packed adds (half the decode VALU of scalar cvt).
__global__ void seg_mean(const u32* __restrict__ f0, const int* __restrict__ o0,
                         const int* __restrict__ l0, u16* __restrict__ out0, int n0,
                         const u32* __restrict__ f1, const int* __restrict__ o1,
                         const int* __restrict__ l1, u16* __restrict__ out1, int n1) {
  const int sel = blockIdx.y;
  const u32* feat = sel ? f1 : f0;
  const int* off = sel ? o1 : o0;
  const int* lst = sel ? l1 : l0;
  u16* out = sel ? out1 : out0;
  const int ndst = sel ? n1 : n0;
  const int wid = threadIdx.x >> 6, lane = threadIdx.x & 63;
  const int node = blockIdx.x * 4 + wid;
  if (node >= ndst) return;
  const int s = off[node], e = off[node + 1];
  const int half = lane >> 5, hl = lane & 31;
  f32x2 a[4];
#pragma unroll
  for (int j = 0; j < 4; ++j) a[j] = (f32x2){0.f, 0.f};
  int i = s;
  for (; i + 8 <= e; i += 8) {
    const int q0 = lst[i + half], q1 = lst[i + 2 + half];
    const int q2 = lst[i + 4 + half], q3 = lst[i + 6 + half];
    const uint2 v0 = *reinterpret_cast<const uint2*>(feat + (size_t)q0 * 64 + hl * 2);
    const uint2 v1 = *reinterpret_cast<const uint2*>(feat + (size_t)q1 * 64 + hl * 2);
    const uint2 v2 = *reinterpret_cast<const uint2*>(feat + (size_t)q2 * 64 + hl * 2);
    const uint2 v3 = *reinterpret_cast<const uint2*>(feat + (size_t)q3 * 64 + hl * 2);
    fp8w_acc(v0.x, a); fp8w_acc(v0.y, a + 2);
    fp8w_acc(v1.x, a); fp8w_acc(v1.y, a + 2);
    fp8w_acc(v2.x, a); fp8w_acc(v2.y, a + 2);
    fp8w_acc(v3.x, a); fp8w_acc(v3.y, a + 2);
  }
  for (; i < e; i += 2) {
    if (i + half < e) {
      const int q = lst[i + half];
      const uint2 v = *reinterpret_cast<const uint2*>(feat + (size_t)q * 64 + hl * 2);
      fp8w_acc(v.x, a);
      fp8w_acc(v.y, a + 2);
    }
  }
#pragma unroll
  for (int j = 0; j < 4; ++j) {
    a[j].x += __shfl_xor(a[j].x, 32, 64);
    a[j].y += __shfl_xor(a[j].y, 32, 64);
  }
  if (half == 0) {
    const float inv = (e > s) ? 1.f / (float)(e - s) : 0.f;
    uint4 o;
    o.x = (u32)f2bf(a[0].x * inv) | ((u32)f2bf(a[0].y * inv) << 16);
    o.y = (u32)f2bf(a[1].x * inv) | ((u32)f2bf(a[1].y * inv) << 16);
    o.z = (u32)f2bf(a[2].x * inv) | ((u32)f2bf(a[2].y * inv) << 16);
    o.w = (u32)f2bf(a[3].x * inv) | ((u32)f2bf(a[3].y * inv) << 16);
    *reinterpret_cast<uint4*>(out + (size_t)node * NDIM + hl * 8) = o;
  }
}

// fused layer-2 epilogue: z = l2norm( mean_{src}(ymsg[src]) + yself[node] )
// ymsg fp8-packed [n][32 u32]; yself bf16 [n][128]. quarter-wave per edge, packed decode.
__global__ void seg_out(const u32* __restrict__ ym0, const u16* __restrict__ ys0,
                        const int* __restrict__ o0, const int* __restrict__ l0,
                        float* __restrict__ z0, int n0,
                        const u32* __restrict__ ym1, const u16* __restrict__ ys1,
                        const int* __restrict__ o1, const int* __restrict__ l1,
                        float* __restrict__ z1, int n1) {
  const int sel = blockIdx.y;
  const u32* ymsg = sel ? ym1 : ym0;
  const u16* yself = sel ? ys1 : ys0;
  const int* off = sel ? o1 : o0;
  const int* lst = sel ? l1 : l0;
  float* zout = sel ? z1 : z0;
  const int ndst = sel ? n1 : n0;
  const int wid = threadIdx.x >> 6, lane = threadIdx.x & 63;
  const int node = blockIdx.x * 4 + wid;
  if (node >= ndst) return;
  const int s = off[node], e = off[node + 1];
  const int q = lane >> 4, ql = lane & 15;
  f32x2 a[4];
#pragma unroll
  for (int j = 0; j < 4; ++j) a[j] = (f32x2){0.f, 0.f};
  int i = s;
  for (; i + 8 <= e; i += 8) {
    const int r0 = lst[i + q], r1 = lst[i + 4 + q];
    const uint2 v0 = *reinterpret_cast<const uint2*>(ymsg + (size_t)r0 * 32 + ql * 2);
    const uint2 v1 = *reinterpret_cast<const uint2*>(ymsg + (size_t)r1 * 32 + ql * 2);
    fp8w_acc(v0.x, a); fp8w_acc(v0.y, a + 2);
    fp8w_acc(v1.x, a); fp8w_acc(v1.y, a + 2);
  }
  for (; i + 4 <= e; i += 4) {
    const int r = lst[i + q];
    const uint2 v = *reinterpret_cast<const uint2*>(ymsg + (size_t)r * 32 + ql * 2);
    fp8w_acc(v.x, a);
    fp8w_acc(v.y, a + 2);
  }
  if (i + q < e) {
    const int r = lst[i + q];
    const uint2 v = *reinterpret_cast<const uint2*>(ymsg + (size_t)r * 32 + ql * 2);
    fp8w_acc(v.x, a);
    fp8w_acc(v.y, a + 2);
  }
#pragma unroll
  for (int j = 0; j < 4; ++j) {
    a[j].x += __shfl_xor(a[j].x, 16, 64);
    a[j].x += __shfl_xor(a[j].x, 32, 64);
    a[j].y += __shfl_xor(a[j].y, 16, 64);
    a[j].y += __shfl_xor(a[j].y, 32, 64);
  }
  const float inv = (e > s) ? 1.f / (float)(e - s) : 0.f;
  const uint4 r = *reinterpret_cast<const uint4*>(yself + (size_t)node * 128 + ql * 8);
  const u32 rw[4] = {r.x, r.y, r.z, r.w};
  float z[8];
  float ss = 0.f;
#pragma unroll
  for (int c = 0; c < 4; ++c) {
    z[2 * c] = a[c].x * inv + bf2f((u16)(rw[c] & 0xffffu));
    z[2 * c + 1] = a[c].y * inv + bf2f((u16)(rw[c] >> 16));
    ss += z[2 * c] * z[2 * c] + z[2 * c + 1] * z[2 * c + 1];
  }
#pragma unroll
  for (int d = 1; d < 16; d <<= 1) ss += __shfl_xor(ss, d, 64);
  const float sc = 1.f / fmaxf(sqrtf(ss), 1e-12f);
  if (q == 0) {
    float4 o0v, o1v;
    o0v.x = z[0] * sc; o0v.y = z[1] * sc; o0v.z = z[2] * sc; o0v.w = z[3] * sc;
    o1v.x = z[4] * sc; o1v.y = z[5] * sc; o1v.z = z[6] * sc; o1v.w = z[7] * sc;
    float* zp = zout + (size_t)node * 128 + ql * 8;
    *reinterpret_cast<float4*>(zp) = o0v;
    *reinterpret_cast<float4*>(zp + 4) = o1v;
  }
}

// Single-buffer 2-barrier GEMM with COALESCED+SWIZZLED staging, two instances via blockIdx.z.
// [R10 structure — best measured.] C = A @ WT^T + bias.
// CAT: A = [Am | Ax] K-concat. SPLIT: msg cols -> fp8 [n][128], self cols -> bf16 [n][128].
template <bool RELU, bool CAT, int KT, bool SPLIT>
__global__ __launch_bounds__(256) void gemm2(
    const u16* __restrict__ Am0, const u16* __restrict__ Ax0,
    const u16* __restrict__ WT0, const float* __restrict__ bias0,
    u16* __restrict__ out0, u8* __restrict__ out8_0, int M0,
    const u16* __restrict__ Am1, const u16* __restrict__ Ax1,
    const u16* __restrict__ WT1, const float* __restrict__ bias1,
    u16* __restrict__ out1, u8* __restrict__ out8_1, int M1,
    int gx, int ldb, int ldo) {
  const int raw = blockIdx.x;
  const int xcd = raw & 7, seq = raw >> 3;
  const int ny = seq & 1;
  const int mt = (seq >> 1) * 8 + xcd;
  if (mt >= gx) return;
  const int sel = blockIdx.z;
  const u16* Am = sel ? Am1 : Am0;
  const u16* Ax = sel ? Ax1 : Ax0;
  const u16* WT = sel ? WT1 : WT0;
  const float* bias = sel ? bias1 : bias0;
  u16* out = sel ? out1 : out0;
  u8* out8 = sel ? out8_1 : out8_0;
  const int M = sel ? M1 : M0;
  const int gm0 = mt * 128;
  if (gm0 >= M) return;
  const int n0 = ny * 128;

  __shared__ u16 As[8192];  // [row 0..127][64 k-elems = 128B], chunk-swizzled
  __shared__ u16 Bs[8192];
  const int tid = threadIdx.x;
  const int wid = tid >> 6, lane = tid & 63;
  const int wr = wid >> 1, wc = wid & 1;

  f32x4 acc[4][4];
  const f32x4 zz = {0.f, 0.f, 0.f, 0.f};
#pragma unroll
  for (int i = 0; i < 4; ++i)
#pragma unroll
    for (int j = 0; j < 4; ++j) acc[i][j] = zz;

  for (int kt = 0; kt < KT; ++kt) {
    const u16* Asrc = CAT ? ((kt < KT / 2) ? Am : Ax) : Am;
    const int koff = CAT ? ((kt & (KT / 2 - 1)) * 64) : kt * 64;
#pragma unroll
    for (int t = 0; t < 4; ++t) {
      const int f = wid * 256 + t * 64 + lane;       // 8 lanes per row, coalesced
      const int row = f >> 3;
      const int ch = (f & 7) ^ (row & 7);            // pre-swizzled global chunk
      int grow = gm0 + row; grow = (grow < M) ? grow : (M - 1);
      const u16* g = Asrc + (size_t)grow * NDIM + koff + ch * 8;
      u16* l = &As[(size_t)f * 8];
      __builtin_amdgcn_global_load_lds((const __attribute__((address_space(1))) void*)g,
                                       (__attribute__((address_space(3))) void*)l, 16, 0, 0);
    }
#pragma unroll
    for (int t = 0; t < 4; ++t) {
      const int f = wid * 256 + t * 64 + lane;
      const int n = f >> 3;
      const int ch = (f & 7) ^ (n & 7);
      const u16* g = WT + (size_t)(n0 + n) * ldb + kt * 64 + ch * 8;
      u16* l = &Bs[(size_t)f * 8];
      __builtin_amdgcn_global_load_lds((const __attribute__((address_space(1))) void*)g,
                                       (__attribute__((address_space(3))) void*)l, 16, 0, 0);
    }
    __syncthreads();
#pragma unroll
    for (int ks = 0; ks < 2; ++ks) {
      const int kc = ks * 4 + (lane >> 4);
      short8 a[4], b[4];
#pragma unroll
      for (int mtt = 0; mtt < 4; ++mtt) {
        const int R = wr * 64 + mtt * 16 + (lane & 15);
        a[mtt] = *reinterpret_cast<const short8*>(&As[(size_t)R * 64 + (kc ^ (R & 7)) * 8]);
      }
#pragma unroll
      for (int nt = 0; nt < 4; ++nt) {
        const int N = wc * 64 + nt * 16 + (lane & 15);
        b[nt] = *reinterpret_cast<const short8*>(&Bs[(size_t)N * 64 + (kc ^ (N & 7)) * 8]);
      }
#pragma unroll
      for (int mtt = 0; mtt < 4; ++mtt)
#pragma unroll
        for (int nt = 0; nt < 4; ++nt)
          acc[mtt][nt] = __builtin_amdgcn_mfma_f32_16x16x32_bf16(a[mtt], b[nt], acc[mtt][nt], 0, 0, 0);
    }
    __syncthreads();
  }

  const int rw = gm0 + wr * 64;
#pragma unroll
  for (int mtt = 0; mtt < 4; ++mtt) {
#pragma unroll
    for (int j = 0; j < 4; ++j) {
      int row = rw + mtt * 16 + ((lane >> 4) << 2) + j;
      if (row >= M) continue;
#pragma unroll
      for (int nt = 0; nt < 4; ++nt) {
        int col = n0 + wc * 64 + nt * 16 + (lane & 15);
        float v = acc[mtt][nt][j] + bias[col];
        if (RELU) v = fmaxf(v, 0.f);
        if constexpr (SPLIT) {
          if (col < 128) out8[(size_t)row * 128 + col] = f2fp8(v);
          else out[(size_t)row * 128 + col - 128] = f2bf(v);
        } else {
          out[(size_t)row * ldo + col] = f2bf(v);
        }
      }
    }
  }
}

extern "C" void kernel_launch(void* const* d_in, const int* in_sizes, int n_in,
                              void* d_out, int out_size, void* d_ws, size_t ws_size,
                              hipStream_t stream) {
  const float* x_drug = (const float*)d_in[0];
  const float* x_prot = (const float*)d_in[1];
  const int* e_dp = (const int*)d_in[2];
  const int* e_pd = (const int*)d_in[3];
  const float* W1l_dp = (const float*)d_in[4];
  const float* W1r_dp = (const float*)d_in[5];
  const float* b1_dp = (const float*)d_in[6];
  const float* W1l_pd = (const float*)d_in[7];
  const float* W1r_pd = (const float*)d_in[8];
  const float* b1_pd = (const float*)d_in[9];
  const float* W2l_dp = (const float*)d_in[10];
  const float* W2r_dp = (const float*)d_in[11];
  const float* b2_dp = (const float*)d_in[12];
  const float* W2l_pd = (const float*)d_in[13];
  const float* W2r_pd = (const float*)d_in[14];
  const float* b2_pd = (const float*)d_in[15];

  const int E = in_sizes[2] / 2;
  const int ND = in_sizes[0] / NDIM;
  const int NP = in_sizes[1] / NDIM;

  const int* dp_src = e_dp;       // drug indices
  const int* dp_dst = e_dp + E;   // protein indices
  const int* pd_src = e_pd;       // protein indices
  const int* pd_dst = e_pd + E;   // drug indices

  char* ws = (char*)d_ws;
  size_t o = 0;
  auto alloc = [&](size_t bytes) -> void* {
    void* p = ws + o;
    o = (o + bytes + 255) & ~(size_t)255;
    return p;
  };
  u16* xd16 = (u16*)alloc((size_t)ND * NDIM * 2);
  u16* xp16 = (u16*)alloc((size_t)NP * NDIM * 2);
  u32* xd8 = (u32*)alloc((size_t)ND * 64 * 4);     // fp8-packed x (drug)
  u32* xp8 = (u32*)alloc((size_t)NP * 64 * 4);     // fp8-packed x (protein)
  u16* mp16 = (u16*)alloc((size_t)NP * NDIM * 2);  // means; reused as yself_p
  u16* md16 = (u16*)alloc((size_t)ND * NDIM * 2);  // means; reused as yself_d
  u16* hp16 = (u16*)alloc((size_t)NP * NDIM * 2);
  u16* hd16 = (u16*)alloc((size_t)ND * NDIM * 2);
  u32* ymd8 = (u32*)alloc((size_t)ND * 32 * 4);    // fp8-packed layer-2 messages (drug)
  u32* ymp8 = (u32*)alloc((size_t)NP * 32 * 4);    // fp8-packed layer-2 messages (protein)
  u16* wt1dp = (u16*)alloc((size_t)256 * KCAT * 2);
  u16* wt1pd = (u16*)alloc((size_t)256 * KCAT * 2);
  u16* wt2d = (u16*)alloc((size_t)256 * 256 * 2);  // [W2l_dp | W2r_pd] for drugs
  u16* wt2p = (u16*)alloc((size_t)256 * 256 * 2);  // [W2l_pd | W2r_dp] for proteins
  float* fbias_d = (float*)alloc(256 * 4);
  float* fbias_p = (float*)alloc(256 * 4);
  int* off_dp = (int*)alloc((size_t)(NP + 1) * 4);
  int* off_pd = (int*)alloc((size_t)(ND + 1) * 4);
  int* lst_dp = (int*)alloc((size_t)E * 4);
  int* lst_pd = (int*)alloc((size_t)E * 4);
  u32* tmp_dp = (u32*)alloc((size_t)E * 4);
  u32* tmp_pd = (u32*)alloc((size_t)E * 4);

  const int nmax = (NP > ND) ? NP : ND;
  const int nbuckets = (nmax + 255) >> 8;
  const int nblk = (E + EB - 1) / EB;
  const int nh = nbuckets * nblk;
  int* hist0 = (int*)alloc((size_t)nh * 4);
  int* hist1 = (int*)alloc((size_t)nh * 4);
  int* hoff0 = (int*)alloc((size_t)(nh + 1) * 4);
  int* hoff1 = (int*)alloc((size_t)(nh + 1) * 4);

  dim3 blk(256);

  // fused setup: cvt (bf16 + fp8) + W1/W2 prep + fbias + radix histogram, one launch
  const int n4d = ND * NDIM / 4, n4p = NP * NDIM / 4;
  const int tA = (n4d + n4p + 255) / 256;
  const int tB = tA + (2 * 256 * KCAT + 255) / 256;
  const int tC = tB + (2 * 256 * 256 + 255) / 256;
  const int tD = tC + 1;
  const int tTotal = tD + 2 * nblk;
  setup_all<<<tTotal, blk, 0, stream>>>(
      x_drug, n4d, x_prot, n4p, xd16, xp16, xd8, xp8,
      W1l_dp, W1r_dp, wt1dp, W1l_pd, W1r_pd, wt1pd,
      W2l_dp, W2r_pd, wt2d, W2l_pd, W2r_dp, wt2p,
      b2_pd, b2_dp, fbias_d, fbias_p,
      dp_dst, pd_dst, E, nblk, nbuckets, hist0, hist1,
      tA, tB, tC, tD);

  // single-kernel scan of both hist arrays
  scan_one<<<2, 1024, 0, stream>>>(hist0, hoff0, hist1, hoff1, nh);

  part_pass<<<dim3(nblk, 2), blk, 0, stream>>>(
      dp_src, dp_dst, tmp_dp, pd_src, pd_dst, tmp_pd, hoff0, hoff1, E, nblk, nbuckets);
  bucket_fill<<<dim3(nbuckets, 2), blk, 0, stream>>>(
      tmp_dp, hoff0, NP, off_dp, lst_dp, tmp_pd, hoff1, ND, off_pd, lst_pd, E, nblk, nbuckets);

  // layer 1: fp8 mean aggregation of raw features (both directions, one launch)
  seg_mean<<<dim3((nmax + 3) / 4, 2), blk, 0, stream>>>(
      xd8, off_dp, lst_dp, mp16, NP, xp8, off_pd, lst_pd, md16, ND);

  // GEMM grid: swizzled pairs, 8-aligned
  const int gx = (nmax + 127) / 128;
  const int gridx = ((gx + 7) / 8) * 16;  // mgrps*2*8

  // layer 1 GEMMs: h = relu([mean | x] @ W1cat + b)   (both node types via z)
  gemm2<true, true, 8, false><<<dim3(gridx, 1, 2), blk, 0, stream>>>(
      mp16, xp16, wt1dp, b1_dp, hp16, (u8*)nullptr, NP,
      md16, xd16, wt1pd, b1_pd, hd16, (u8*)nullptr, ND, gx, KCAT, 256);

  // layer 2 transform-first, split outputs: ymsg fp8 [n][128], yself bf16 [n][128]
  u16* yself_d = md16;  // reuse dead mean buffers
  u16* yself_p = mp16;
  gemm2<false, false, 4, true><<<dim3(gridx, 1, 2), blk, 0, stream>>>(
      hd16, hd16, wt2d, fbias_d, yself_d, (u8*)ymd8, ND,
      hp16, hp16, wt2p, fbias_p, yself_p, (u8*)ymp8, NP, gx, 256, 256);

  // fused: fp8 mean-gather of messages + self + L2 normalize -> d_out
  float* zd = (float*)d_out;
  float* zp = zd + (size_t)ND * 128;
  seg_out<<<dim3((nmax + 3) / 4, 2), blk, 0, stream>>>(
      ymp8, yself_d, off_pd, lst_pd, zd, ND, ymd8, yself_p, off_dp, lst_dp, zp, NP);
}

// Round 16
// 329.555 us; speedup vs baseline: 1.1801x; 1.0020x over previous
//
#include <hip/hip_runtime.h>

typedef unsigned short u16;
typedef unsigned int u32;
typedef unsigned char u8;
typedef __attribute__((ext_vector_type(8))) short short8;
typedef __attribute__((ext_vector_type(4))) float f32x4;
typedef __attribute__((ext_vector_type(2))) float f32x2;

#define NDIM 256
#define KCAT 512
#define EB 8192      // edges per partition block
#define NBK_MAX 256  // max buckets (node>>8)

__device__ __forceinline__ float bf2f(u16 u) {
  union { u32 i; float f; } v; v.i = ((u32)u) << 16; return v.f;
}
__device__ __forceinline__ u16 f2bf(float f) {
  union { float f; u32 i; } v; v.f = f;
  u32 u = v.i;
  u32 r = (u + 0x7fffu + ((u >> 16) & 1u)) >> 16;  // RNE
  return (u16)r;
}
// pack 4 floats -> 4 fp8 e4m3 bytes (OCP on gfx950), HW RNE
__device__ __forceinline__ u32 pk4_fp8(float a, float b, float c, float d) {
  u32 p = __builtin_amdgcn_cvt_pk_fp8_f32(a, b, 0u, 0);
  p = __builtin_amdgcn_cvt_pk_fp8_f32(c, d, p, 1);
  return p;
}
__device__ __forceinline__ u8 f2fp8(float f) {
  return (u8)(__builtin_amdgcn_cvt_pk_fp8_f32(f, f, 0u, 0) & 0xffu);
}
// packed fp8 pair decode: bytes [0,1] (lo) or [2,3] (hi) of w -> float2, one VALU op
#if __has_builtin(__builtin_amdgcn_cvt_pk_f32_fp8)
__device__ __forceinline__ f32x2 fp8pk_lo(u32 w) { return __builtin_amdgcn_cvt_pk_f32_fp8(w, false); }
__device__ __forceinline__ f32x2 fp8pk_hi(u32 w) { return __builtin_amdgcn_cvt_pk_f32_fp8(w, true); }
#else
__device__ __forceinline__ f32x2 fp8pk_lo(u32 w) {
  f32x2 r; r.x = __builtin_amdgcn_cvt_f32_fp8(w, 0); r.y = __builtin_amdgcn_cvt_f32_fp8(w, 1); return r;
}
__device__ __forceinline__ f32x2 fp8pk_hi(u32 w) {
  f32x2 r; r.x = __builtin_amdgcn_cvt_f32_fp8(w, 2); r.y = __builtin_amdgcn_cvt_f32_fp8(w, 3); return r;
}
#endif
// accumulate one u32 (4 fp8) into a[0..1] (f32x2 pairs)
__device__ __forceinline__ void fp8w_acc(u32 w, f32x2* a) {
  a[0] += fp8pk_lo(w);
  a[1] += fp8pk_hi(w);
}

// Horizontal fusion of all independent setup work (one launch):
//   [0,tA):    cvt fp32 -> bf16 AND fp8 of both feature tables
//   [tA,tB):   W1 transpose+K-concat (both directions)
//   [tB,tC):   W2 transpose+N-concat (both node types)
//   [tC,tD):   fused layer-2 bias vectors
//   [tD,...):  per-block LDS histogram of dst buckets (radix pass 1)
__global__ void setup_all(
    const float* __restrict__ xd, int n4d, const float* __restrict__ xp, int n4p,
    u16* __restrict__ xd16, u16* __restrict__ xp16,
    u32* __restrict__ xd8, u32* __restrict__ xp8,
    const float* __restrict__ W1l0, const float* __restrict__ W1r0, u16* __restrict__ WT10,
    const float* __restrict__ W1l1, const float* __restrict__ W1r1, u16* __restrict__ WT11,
    const float* __restrict__ W2l0, const float* __restrict__ W2r0, u16* __restrict__ WT20,
    const float* __restrict__ W2l1, const float* __restrict__ W2r1, u16* __restrict__ WT21,
    const float* __restrict__ b2d, const float* __restrict__ b2p,
    float* __restrict__ fd, float* __restrict__ fp,
    const int* __restrict__ dpd, const int* __restrict__ pdd, int E,
    int nblk, int nbuckets, int* __restrict__ h0, int* __restrict__ h1,
    int tA, int tB, int tC, int tD) {
  __shared__ int h[NBK_MAX];
  const int b = blockIdx.x;
  const int tid = threadIdx.x;
  if (b < tA) {
    int i = b * 256 + tid;
    const float* in; u16* out; u32* out8; int j;
    if (i < n4d) { in = xd; out = xd16; out8 = xd8; j = i; }
    else { j = i - n4d; if (j >= n4p) return; in = xp; out = xp16; out8 = xp8; }
    const float4 v = reinterpret_cast<const float4*>(in)[j];
    u32 lo = (u32)f2bf(v.x) | ((u32)f2bf(v.y) << 16);
    u32 hi = (u32)f2bf(v.z) | ((u32)f2bf(v.w) << 16);
    reinterpret_cast<uint2*>(out)[j] = make_uint2(lo, hi);
    out8[j] = pk4_fp8(v.x, v.y, v.z, v.w);
  } else if (b < tB) {
    int gidx = (b - tA) * 256 + tid;            // 2 x 131072
    const int sel = gidx >> 17;
    const int idx = gidx & 131071;
    const float* Wl = sel ? W1l1 : W1l0;
    const float* Wr = sel ? W1r1 : W1r0;
    u16* WT = sel ? WT11 : WT10;
    int n = idx >> 9, k = idx & 511;
    float v = (k < 256) ? Wl[k * 256 + n] : Wr[(k - 256) * 256 + n];
    WT[idx] = f2bf(v);
  } else if (b < tC) {
    int gidx = (b - tB) * 256 + tid;            // 2 x 65536
    const int sel = gidx >> 16;
    const int idx = gidx & 65535;
    const float* Wl = sel ? W2l1 : W2l0;
    const float* Wr = sel ? W2r1 : W2r0;
    u16* WT = sel ? WT21 : WT20;
    int n = idx >> 8, k = idx & 255;
    float v = (n < 128) ? Wl[k * 128 + n] : Wr[k * 128 + (n - 128)];
    WT[idx] = f2bf(v);
  } else if (b < tD) {
    fd[tid] = (tid < 128) ? 0.f : b2d[tid - 128];
    fp[tid] = (tid < 128) ? 0.f : b2p[tid - 128];
  } else {
    const int hb = b - tD;
    const int sel = (hb >= nblk);
    const int blk = sel ? hb - nblk : hb;
    const int* dst = sel ? pdd : dpd;
    int* hist = sel ? h1 : h0;
    for (int x = tid; x < nbuckets; x += 256) h[x] = 0;
    __syncthreads();
    const int e0 = blk * EB;
    const int e1 = (e0 + EB < E) ? (e0 + EB) : E;
    for (int i = e0 + tid; i < e1; i += 256) atomicAdd(&h[dst[i] >> 8], 1);
    __syncthreads();
    for (int x = tid; x < nbuckets; x += 256) hist[x * nblk + blk] = h[x];
  }
}

// single-kernel exclusive scan of both hist arrays (one block per direction, 1024 thr)
#define SCAN_PER 20
__global__ void scan_one(const int* __restrict__ h0, int* __restrict__ o0,
                         const int* __restrict__ h1, int* __restrict__ o1, int nh) {
  const int sel = blockIdx.x;
  const int* h = sel ? h1 : h0;
  int* off = sel ? o1 : o0;
  const int tid = threadIdx.x;  // 1024
  int v[SCAN_PER];
  int s = 0;
  const int i0 = tid * SCAN_PER;
#pragma unroll
  for (int j = 0; j < SCAN_PER; ++j) {
    int i = i0 + j;
    v[j] = (i < nh) ? h[i] : 0;
    s += v[j];
  }
  __shared__ int tile[1024];
  tile[tid] = s;
  __syncthreads();
  for (int d = 1; d < 1024; d <<= 1) {
    int t = (tid >= d) ? tile[tid - d] : 0;
    __syncthreads();
    tile[tid] += t;
    __syncthreads();
  }
  int run = tile[tid] - s;  // exclusive prefix of this thread's chunk
#pragma unroll
  for (int j = 0; j < SCAN_PER; ++j) {
    int i = i0 + j;
    run += v[j];
    if (i < nh) off[i + 1] = run;
  }
  if (tid == 0) off[0] = 0;
}

// radix-partition pass 2: LDS cursors = scanned (bucket,blk) offsets -> global slot directly.
__global__ void part_pass(const int* __restrict__ s0, const int* __restrict__ d0, u32* __restrict__ t0,
                          const int* __restrict__ s1, const int* __restrict__ d1, u32* __restrict__ t1,
                          const int* __restrict__ ho0, const int* __restrict__ ho1,
                          int E, int nblk, int nbuckets) {
  const int sel = blockIdx.y;
  const int* src = sel ? s1 : s0;
  const int* dst = sel ? d1 : d0;
  const int* hoff = sel ? ho1 : ho0;
  u32* tmp = sel ? t1 : t0;
  const int blk = blockIdx.x;
  __shared__ int cur[NBK_MAX];
  for (int b = threadIdx.x; b < nbuckets; b += 256) cur[b] = hoff[b * nblk + blk];
  __syncthreads();
  const int e0 = blk * EB;
  const int e1 = (e0 + EB < E) ? (e0 + EB) : E;
  for (int i = e0 + threadIdx.x; i < e1; i += 256) {
    const int d = dst[i];
    const int p = atomicAdd(&cur[d >> 8], 1);
    tmp[p] = ((u32)(d & 255) << 16) | (u32)src[i];
  }
}

// phase C: one block per 256-node bucket; derives per-node off[] (LDS histogram + scan),
// then scatters u16 lst within the bucket's window.
__global__ void bucket_fill(const u32* __restrict__ t0, const int* __restrict__ ho0,
                            int n0, int* __restrict__ off0, u16* __restrict__ l0,
                            const u32* __restrict__ t1, const int* __restrict__ ho1,
                            int n1, int* __restrict__ off1, u16* __restrict__ l1,
                            int E, int nblk, int nbuckets) {
  const int sel = blockIdx.y;
  const u32* tmp = sel ? t1 : t0;
  const int* hoff = sel ? ho1 : ho0;
  const int n = sel ? n1 : n0;
  int* off = sel ? off1 : off0;
  u16* lst = sel ? l1 : l0;
  const int b = blockIdx.x;
  const int node0 = b << 8;
  if (node0 >= n) return;
  const int nodes = (n - node0 < 256) ? (n - node0) : 256;
  const int base = hoff[b * nblk];
  const int bend = hoff[(b + 1) * nblk];
  const int t = threadIdx.x, lane = t & 63, w = t >> 6;
  __shared__ int cnt[256];
  __shared__ int wsum[4];
  cnt[t] = 0;
  __syncthreads();
  for (int i = base + t; i < bend; i += 256) atomicAdd(&cnt[tmp[i] >> 16], 1);
  __syncthreads();
  const int v = cnt[t];
  int inc = v;
#pragma unroll
  for (int d = 1; d < 64; d <<= 1) {
    int x = __shfl_up(inc, d, 64);
    if (lane >= d) inc += x;
  }
  if (lane == 63) wsum[w] = inc;
  __syncthreads();
  int wb = 0;
  for (int q = 0; q < w; ++q) wb += wsum[q];
  const int excl = base + (inc - v) + wb;
  __syncthreads();
  cnt[t] = excl;
  if (t < nodes) off[node0 + t] = excl;
  if (node0 + nodes == n && t == 0) off[n] = E;
  __syncthreads();
  for (int i = base + t; i < bend; i += 256) {
    const u32 pk = tmp[i];
    const int p = atomicAdd(&cnt[pk >> 16], 1);
    lst[p] = (u16)(pk & 0xffffu);
  }
}

// fp8 mean-gather, packed decode, SPLIT accumulator sets (halved add-chain depth).
// feat fp8-packed [node][64 u32]; u16 edge list. One wave per dst node, half-wave per
// edge (uint2 = 8 fp8/lane), 8 edges in flight.
__global__ void seg_mean(const u32* __restrict__ f0, const int* __restrict__ o0,
                         const u16* __restrict__ l0, u16* __restrict__ out0, int n0,
                         const u32* __restrict__ f1, const int* __restrict__ o1,
                         const u16* __restrict__ l1, u16* __restrict__ out1, int n1) {
  const int sel = blockIdx.y;
  const u32* feat = sel ? f1 : f0;
  const int* off = sel ? o1 : o0;
  const u16* lst = sel ? l1 : l0;
  u16* out = sel ? out1 : out0;
  const int ndst = sel ? n1 : n0;
  const int wid = threadIdx.x >> 6, lane = threadIdx.x & 63;
  const int node = blockIdx.x * 4 + wid;
  if (node >= ndst) return;
  const int s = off[node], e = off[node + 1];
  const int half = lane >> 5, hl = lane & 31;
  f32x2 a[4], b[4];
#pragma unroll
  for (int j = 0; j < 4; ++j) { a[j] = (f32x2){0.f, 0.f}; b[j] = (f32x2){0.f, 0.f}; }
  int i = s;
  for (; i + 8 <= e; i += 8) {
    const int q0 = lst[i + half], q1 = lst[i + 2 + half];
    const int q2 = lst[i + 4 + half], q3 = lst[i + 6 + half];
    const uint2 v0 = *reinterpret_cast<const uint2*>(feat + (size_t)q0 * 64 + hl * 2);
    const uint2 v1 = *reinterpret_cast<const uint2*>(feat + (size_t)q1 * 64 + hl * 2);
    const uint2 v2 = *reinterpret_cast<const uint2*>(feat + (size_t)q2 * 64 + hl * 2);
    const uint2 v3 = *reinterpret_cast<const uint2*>(feat + (size_t)q3 * 64 + hl * 2);
    fp8w_acc(v0.x, a); fp8w_acc(v0.y, a + 2);   // set A: edges 0,1
    fp8w_acc(v1.x, a); fp8w_acc(v1.y, a + 2);
    fp8w_acc(v2.x, b); fp8w_acc(v2.y, b + 2);   // set B: edges 2,3
    fp8w_acc(v3.x, b); fp8w_acc(v3.y, b + 2);
  }
  for (; i < e; i += 2) {
    if (i + half < e) {
      const int q = lst[i + half];
      const uint2 v = *reinterpret_cast<const uint2*>(feat + (size_t)q * 64 + hl * 2);
      fp8w_acc(v.x, a);
      fp8w_acc(v.y, a + 2);
    }
  }
#pragma unroll
  for (int j = 0; j < 4; ++j) a[j] += b[j];  // merge sets
#pragma unroll
  for (int j = 0; j < 4; ++j) {
    a[j].x += __shfl_xor(a[j].x, 32, 64);
    a[j].y += __shfl_xor(a[j].y, 32, 64);
  }
  if (half == 0) {
    const float inv = (e > s) ? 1.f / (float)(e - s) : 0.f;
    uint4 o;
    o.x = (u32)f2bf(a[0].x * inv) | ((u32)f2bf(a[0].y * inv) << 16);
    o.y = (u32)f2bf(a[1].x * inv) | ((u32)f2bf(a[1].y * inv) << 16);
    o.z = (u32)f2bf(a[2].x * inv) | ((u32)f2bf(a[2].y * inv) << 16);
    o.w = (u32)f2bf(a[3].x * inv) | ((u32)f2bf(a[3].y * inv) << 16);
    *reinterpret_cast<uint4*>(out + (size_t)node * NDIM + hl * 8) = o;
  }
}

// fused layer-2 epilogue: z = l2norm( mean_{src}(ymsg[src]) + yself[node] )
// ymsg fp8-packed [n][32 u32]; yself bf16 [n][128]; u16 edge list.
// quarter-wave per edge, packed decode, split accumulator sets.
__global__ void seg_out(const u32* __restrict__ ym0, const u16* __restrict__ ys0,
                        const int* __restrict__ o0, const u16* __restrict__ l0,
                        float* __restrict__ z0, int n0,
                        const u32* __restrict__ ym1, const u16* __restrict__ ys1,
                        const int* __restrict__ o1, const u16* __restrict__ l1,
                        float* __restrict__ z1, int n1) {
  const int sel = blockIdx.y;
  const u32* ymsg = sel ? ym1 : ym0;
  const u16* yself = sel ? ys1 : ys0;
  const int* off = sel ? o1 : o0;
  const u16* lst = sel ? l1 : l0;
  float* zout = sel ? z1 : z0;
  const int ndst = sel ? n1 : n0;
  const int wid = threadIdx.x >> 6, lane = threadIdx.x & 63;
  const int node = blockIdx.x * 4 + wid;
  if (node >= ndst) return;
  const int s = off[node], e = off[node + 1];
  const int q = lane >> 4, ql = lane & 15;
  f32x2 a[4], b[4];
#pragma unroll
  for (int j = 0; j < 4; ++j) { a[j] = (f32x2){0.f, 0.f}; b[j] = (f32x2){0.f, 0.f}; }
  int i = s;
  for (; i + 8 <= e; i += 8) {
    const int r0 = lst[i + q], r1 = lst[i + 4 + q];
    const uint2 v0 = *reinterpret_cast<const uint2*>(ymsg + (size_t)r0 * 32 + ql * 2);
    const uint2 v1 = *reinterpret_cast<const uint2*>(ymsg + (size_t)r1 * 32 + ql * 2);
    fp8w_acc(v0.x, a); fp8w_acc(v0.y, a + 2);
    fp8w_acc(v1.x, b); fp8w_acc(v1.y, b + 2);
  }
  for (; i + 4 <= e; i += 4) {
    const int r = lst[i + q];
    const uint2 v = *reinterpret_cast<const uint2*>(ymsg + (size_t)r * 32 + ql * 2);
    fp8w_acc(v.x, a);
    fp8w_acc(v.y, a + 2);
  }
  if (i + q < e) {
    const int r = lst[i + q];
    const uint2 v = *reinterpret_cast<const uint2*>(ymsg + (size_t)r * 32 + ql * 2);
    fp8w_acc(v.x, a);
    fp8w_acc(v.y, a + 2);
  }
#pragma unroll
  for (int j = 0; j < 4; ++j) a[j] += b[j];
#pragma unroll
  for (int j = 0; j < 4; ++j) {
    a[j].x += __shfl_xor(a[j].x, 16, 64);
    a[j].x += __shfl_xor(a[j].x, 32, 64);
    a[j].y += __shfl_xor(a[j].y, 16, 64);
    a[j].y += __shfl_xor(a[j].y, 32, 64);
  }
  const float inv = (e > s) ? 1.f / (float)(e - s) : 0.f;
  const uint4 r = *reinterpret_cast<const uint4*>(yself + (size_t)node * 128 + ql * 8);
  const u32 rw[4] = {r.x, r.y, r.z, r.w};
  float z[8];
  float ss = 0.f;
#pragma unroll
  for (int c = 0; c < 4; ++c) {
    z[2 * c] = a[c].x * inv + bf2f((u16)(rw[c] & 0xffffu));
    z[2 * c + 1] = a[c].y * inv + bf2f((u16)(rw[c] >> 16));
    ss += z[2 * c] * z[2 * c] + z[2 * c + 1] * z[2 * c + 1];
  }
#pragma unroll
  for (int d = 1; d < 16; d <<= 1) ss += __shfl_xor(ss, d, 64);
  const float sc = 1.f / fmaxf(sqrtf(ss), 1e-12f);
  if (q == 0) {
    float4 o0v, o1v;
    o0v.x = z[0] * sc; o0v.y = z[1] * sc; o0v.z = z[2] * sc; o0v.w = z[3] * sc;
    o1v.x = z[4] * sc; o1v.y = z[5] * sc; o1v.z = z[6] * sc; o1v.w = z[7] * sc;
    float* zp = zout + (size_t)node * 128 + ql * 8;
    *reinterpret_cast<float4*>(zp) = o0v;
    *reinterpret_cast<float4*>(zp + 4) = o1v;
  }
}

// Single-buffer 2-barrier GEMM with COALESCED+SWIZZLED staging, two instances via blockIdx.z.
// [R10 structure — best measured.] C = A @ WT^T + bias.
// CAT: A = [Am | Ax] K-concat. SPLIT: msg cols -> fp8 [n][128], self cols -> bf16 [n][128].
template <bool RELU, bool CAT, int KT, bool SPLIT>
__global__ __launch_bounds__(256) void gemm2(
    const u16* __restrict__ Am0, const u16* __restrict__ Ax0,
    const u16* __restrict__ WT0, const float* __restrict__ bias0,
    u16* __restrict__ out0, u8* __restrict__ out8_0, int M0,
    const u16* __restrict__ Am1, const u16* __restrict__ Ax1,
    const u16* __restrict__ WT1, const float* __restrict__ bias1,
    u16* __restrict__ out1, u8* __restrict__ out8_1, int M1,
    int gx, int ldb, int ldo) {
  const int raw = blockIdx.x;
  const int xcd = raw & 7, seq = raw >> 3;
  const int ny = seq & 1;
  const int mt = (seq >> 1) * 8 + xcd;
  if (mt >= gx) return;
  const int sel = blockIdx.z;
  const u16* Am = sel ? Am1 : Am0;
  const u16* Ax = sel ? Ax1 : Ax0;
  const u16* WT = sel ? WT1 : WT0;
  const float* bias = sel ? bias1 : bias0;
  u16* out = sel ? out1 : out0;
  u8* out8 = sel ? out8_1 : out8_0;
  const int M = sel ? M1 : M0;
  const int gm0 = mt * 128;
  if (gm0 >= M) return;
  const int n0 = ny * 128;

  __shared__ u16 As[8192];  // [row 0..127][64 k-elems = 128B], chunk-swizzled
  __shared__ u16 Bs[8192];
  const int tid = threadIdx.x;
  const int wid = tid >> 6, lane = tid & 63;
  const int wr = wid >> 1, wc = wid & 1;

  f32x4 acc[4][4];
  const f32x4 zz = {0.f, 0.f, 0.f, 0.f};
#pragma unroll
  for (int i = 0; i < 4; ++i)
#pragma unroll
    for (int j = 0; j < 4; ++j) acc[i][j] = zz;

  for (int kt = 0; kt < KT; ++kt) {
    const u16* Asrc = CAT ? ((kt < KT / 2) ? Am : Ax) : Am;
    const int koff = CAT ? ((kt & (KT / 2 - 1)) * 64) : kt * 64;
#pragma unroll
    for (int t = 0; t < 4; ++t) {
      const int f = wid * 256 + t * 64 + lane;       // 8 lanes per row, coalesced
      const int row = f >> 3;
      const int ch = (f & 7) ^ (row & 7);            // pre-swizzled global chunk
      int grow = gm0 + row; grow = (grow < M) ? grow : (M - 1);
      const u16* g = Asrc + (size_t)grow * NDIM + koff + ch * 8;
      u16* l = &As[(size_t)f * 8];
      __builtin_amdgcn_global_load_lds((const __attribute__((address_space(1))) void*)g,
                                       (__attribute__((address_space(3))) void*)l, 16, 0, 0);
    }
#pragma unroll
    for (int t = 0; t < 4; ++t) {
      const int f = wid * 256 + t * 64 + lane;
      const int n = f >> 3;
      const int ch = (f & 7) ^ (n & 7);
      const u16* g = WT + (size_t)(n0 + n) * ldb + kt * 64 + ch * 8;
      u16* l = &Bs[(size_t)f * 8];
      __builtin_amdgcn_global_load_lds((const __attribute__((address_space(1))) void*)g,
                                       (__attribute__((address_space(3))) void*)l, 16, 0, 0);
    }
    __syncthreads();
#pragma unroll
    for (int ks = 0; ks < 2; ++ks) {
      const int kc = ks * 4 + (lane >> 4);
      short8 a[4], b[4];
#pragma unroll
      for (int mtt = 0; mtt < 4; ++mtt) {
        const int R = wr * 64 + mtt * 16 + (lane & 15);
        a[mtt] = *reinterpret_cast<const short8*>(&As[(size_t)R * 64 + (kc ^ (R & 7)) * 8]);
      }
#pragma unroll
      for (int nt = 0; nt < 4; ++nt) {
        const int N = wc * 64 + nt * 16 + (lane & 15);
        b[nt] = *reinterpret_cast<const short8*>(&Bs[(size_t)N * 64 + (kc ^ (N & 7)) * 8]);
      }
#pragma unroll
      for (int mtt = 0; mtt < 4; ++mtt)
#pragma unroll
        for (int nt = 0; nt < 4; ++nt)
          acc[mtt][nt] = __builtin_amdgcn_mfma_f32_16x16x32_bf16(a[mtt], b[nt], acc[mtt][nt], 0, 0, 0);
    }
    __syncthreads();
  }

  const int rw = gm0 + wr * 64;
#pragma unroll
  for (int mtt = 0; mtt < 4; ++mtt) {
#pragma unroll
    for (int j = 0; j < 4; ++j) {
      int row = rw + mtt * 16 + ((lane >> 4) << 2) + j;
      if (row >= M) continue;
#pragma unroll
      for (int nt = 0; nt < 4; ++nt) {
        int col = n0 + wc * 64 + nt * 16 + (lane & 15);
        float v = acc[mtt][nt][j] + bias[col];
        if (RELU) v = fmaxf(v, 0.f);
        if constexpr (SPLIT) {
          if (col < 128) out8[(size_t)row * 128 + col] = f2fp8(v);
          else out[(size_t)row * 128 + col - 128] = f2bf(v);
        } else {
          out[(size_t)row * ldo + col] = f2bf(v);
        }
      }
    }
  }
}

extern "C" void kernel_launch(void* const* d_in, const int* in_sizes, int n_in,
                              void* d_out, int out_size, void* d_ws, size_t ws_size,
                              hipStream_t stream) {
  const float* x_drug = (const float*)d_in[0];
  const float* x_prot = (const float*)d_in[1];
  const int* e_dp = (const int*)d_in[2];
  const int* e_pd = (const int*)d_in[3];
  const float* W1l_dp = (const float*)d_in[4];
  const float* W1r_dp = (const float*)d_in[5];
  const float* b1_dp = (const float*)d_in[6];
  const float* W1l_pd = (const float*)d_in[7];
  const float* W1r_pd = (const float*)d_in[8];
  const float* b1_pd = (const float*)d_in[9];
  const float* W2l_dp = (const float*)d_in[10];
  const float* W2r_dp = (const float*)d_in[11];
  const float* b2_dp = (const float*)d_in[12];
  const float* W2l_pd = (const float*)d_in[13];
  const float* W2r_pd = (const float*)d_in[14];
  const float* b2_pd = (const float*)d_in[15];

  const int E = in_sizes[2] / 2;
  const int ND = in_sizes[0] / NDIM;
  const int NP = in_sizes[1] / NDIM;

  const int* dp_src = e_dp;       // drug indices
  const int* dp_dst = e_dp + E;   // protein indices
  const int* pd_src = e_pd;       // protein indices
  const int* pd_dst = e_pd + E;   // drug indices

  char* ws = (char*)d_ws;
  size_t o = 0;
  auto alloc = [&](size_t bytes) -> void* {
    void* p = ws + o;
    o = (o + bytes + 255) & ~(size_t)255;
    return p;
  };
  u16* xd16 = (u16*)alloc((size_t)ND * NDIM * 2);
  u16* xp16 = (u16*)alloc((size_t)NP * NDIM * 2);
  u32* xd8 = (u32*)alloc((size_t)ND * 64 * 4);     // fp8-packed x (drug)
  u32* xp8 = (u32*)alloc((size_t)NP * 64 * 4);     // fp8-packed x (protein)
  u16* mp16 = (u16*)alloc((size_t)NP * NDIM * 2);  // means; reused as yself_p
  u16* md16 = (u16*)alloc((size_t)ND * NDIM * 2);  // means; reused as yself_d
  u16* hp16 = (u16*)alloc((size_t)NP * NDIM * 2);
  u16* hd16 = (u16*)alloc((size_t)ND * NDIM * 2);
  u32* ymd8 = (u32*)alloc((size_t)ND * 32 * 4);    // fp8-packed layer-2 messages (drug)
  u32* ymp8 = (u32*)alloc((size_t)NP * 32 * 4);    // fp8-packed layer-2 messages (protein)
  u16* wt1dp = (u16*)alloc((size_t)256 * KCAT * 2);
  u16* wt1pd = (u16*)alloc((size_t)256 * KCAT * 2);
  u16* wt2d = (u16*)alloc((size_t)256 * 256 * 2);  // [W2l_dp | W2r_pd] for drugs
  u16* wt2p = (u16*)alloc((size_t)256 * 256 * 2);  // [W2l_pd | W2r_dp] for proteins
  float* fbias_d = (float*)alloc(256 * 4);
  float* fbias_p = (float*)alloc(256 * 4);
  int* off_dp = (int*)alloc((size_t)(NP + 1) * 4);
  int* off_pd = (int*)alloc((size_t)(ND + 1) * 4);
  u16* lst_dp = (u16*)alloc((size_t)E * 2);
  u16* lst_pd = (u16*)alloc((size_t)E * 2);
  u32* tmp_dp = (u32*)alloc((size_t)E * 4);
  u32* tmp_pd = (u32*)alloc((size_t)E * 4);

  const int nmax = (NP > ND) ? NP : ND;
  const int nbuckets = (nmax + 255) >> 8;
  const int nblk = (E + EB - 1) / EB;
  const int nh = nbuckets * nblk;
  int* hist0 = (int*)alloc((size_t)nh * 4);
  int* hist1 = (int*)alloc((size_t)nh * 4);
  int* hoff0 = (int*)alloc((size_t)(nh + 1) * 4);
  int* hoff1 = (int*)alloc((size_t)(nh + 1) * 4);

  dim3 blk(256);

  // fused setup: cvt (bf16 + fp8) + W1/W2 prep + fbias + radix histogram, one launch
  const int n4d = ND * NDIM / 4, n4p = NP * NDIM / 4;
  const int tA = (n4d + n4p + 255) / 256;
  const int tB = tA + (2 * 256 * KCAT + 255) / 256;
  const int tC = tB + (2 * 256 * 256 + 255) / 256;
  const int tD = tC + 1;
  const int tTotal = tD + 2 * nblk;
  setup_all<<<tTotal, blk, 0, stream>>>(
      x_drug, n4d, x_prot, n4p, xd16, xp16, xd8, xp8,
      W1l_dp, W1r_dp, wt1dp, W1l_pd, W1r_pd, wt1pd,
      W2l_dp, W2r_pd, wt2d, W2l_pd, W2r_dp, wt2p,
      b2_pd, b2_dp, fbias_d, fbias_p,
      dp_dst, pd_dst, E, nblk, nbuckets, hist0, hist1,
      tA, tB, tC, tD);

  // single-kernel scan of both hist arrays
  scan_one<<<2, 1024, 0, stream>>>(hist0, hoff0, hist1, hoff1, nh);

  part_pass<<<dim3(nblk, 2), blk, 0, stream>>>(
      dp_src, dp_dst, tmp_dp, pd_src, pd_dst, tmp_pd, hoff0, hoff1, E, nblk, nbuckets);
  bucket_fill<<<dim3(nbuckets, 2), blk, 0, stream>>>(
      tmp_dp, hoff0, NP, off_dp, lst_dp, tmp_pd, hoff1, ND, off_pd, lst_pd, E, nblk, nbuckets);

  // layer 1: fp8 mean aggregation of raw features (both directions, one launch)
  seg_mean<<<dim3((nmax + 3) / 4, 2), blk, 0, stream>>>(
      xd8, off_dp, lst_dp, mp16, NP, xp8, off_pd, lst_pd, md16, ND);

  // GEMM grid: swizzled pairs, 8-aligned
  const int gx = (nmax + 127) / 128;
  const int gridx = ((gx + 7) / 8) * 16;  // mgrps*2*8

  // layer 1 GEMMs: h = relu([mean | x] @ W1cat + b)   (both node types via z)
  gemm2<true, true, 8, false><<<dim3(gridx, 1, 2), blk, 0, stream>>>(
      mp16, xp16, wt1dp, b1_dp, hp16, (u8*)nullptr, NP,
      md16, xd16, wt1pd, b1_pd, hd16, (u8*)nullptr, ND, gx, KCAT, 256);

  // layer 2 transform-first, split outputs: ymsg fp8 [n][128], yself bf16 [n][128]
  u16* yself_d = md16;  // reuse dead mean buffers
  u16* yself_p = mp16;
  gemm2<false, false, 4, true><<<dim3(gridx, 1, 2), blk, 0, stream>>>(
      hd16, hd16, wt2d, fbias_d, yself_d, (u8*)ymd8, ND,
      hp16, hp16, wt2p, fbias_p, yself_p, (u8*)ymp8, NP, gx, 256, 256);

  // fused: fp8 mean-gather of messages + self + L2 normalize -> d_out
  float* zd = (float*)d_out;
  float* zp = zd + (size_t)ND * 128;
  seg_out<<<dim3((nmax + 3) / 4, 2), blk, 0, stream>>>(
      ymp8, yself_d, off_pd, lst_pd, zd, ND, ymd8, yself_p, off_dp, lst_dp, zp, NP);
}